// Round 8
// baseline (2911.807 us; speedup 1.0000x reference)
//
#include <hip/hip_runtime.h>
#include <math.h>

#define B_ 128
#define T_ 100
#define RS 72      // padded row stride (words); data cols [4..67]; [0..3],[68..71] zero
#define ZS1 68     // zs/cb stride: 68 mod 32 = 4 -> ch spreads banks (r7 used 64 -> 16-way conflicts)

// ---------------------------------------------------------------------------
// Fast transcendentals (~1e-6 rel err; threshold 1.27e-4)
// ---------------------------------------------------------------------------
__device__ __forceinline__ float frcp_(float x){ return __builtin_amdgcn_rcpf(x); }
__device__ __forceinline__ float fsig_(float x){ return frcp_(1.f + __expf(-x)); }
__device__ __forceinline__ float ftanh_(float x){ float e = __expf(2.f*x); return 1.f - 2.f*frcp_(e+1.f); }
__device__ __forceinline__ float gate1(float zi, float zf, float zo, float zg, float& c){
    float cc = fsig_(zf)*c + fsig_(zi)*ftanh_(zg);
    c = cc;
    return fsig_(zo)*ftanh_(cc);
}
__device__ __forceinline__ float4 ldf4(const float* p){ return *reinterpret_cast<const float4*>(p); }
__device__ __forceinline__ void stf4(float* p, float4 v){ *reinterpret_cast<float4*>(p) = v; }
__device__ __forceinline__ float4 add4(float4 a, float4 b){
    return make_float4(a.x+b.x, a.y+b.y, a.z+b.z, a.w+b.w);
}
__device__ __forceinline__ float4 gate4(float4 zi, float4 zf, float4 zo, float4 zg,
                                        float bi, float bf, float bo, float bg, float4& c){
    float4 h;
    h.x = gate1(zi.x+bi, zf.x+bf, zo.x+bo, zg.x+bg, c.x);
    h.y = gate1(zi.y+bi, zf.y+bf, zo.y+bo, zg.y+bg, c.y);
    h.z = gate1(zi.z+bi, zf.z+bf, zo.z+bo, zg.z+bg, c.z);
    h.w = gate1(zi.w+bi, zf.w+bf, zo.w+bo, zg.w+bg, c.w);
    return h;
}

// 4 gates x 4 columns FMA: W = float4 of gate weights (i,f,o,g)
#define FMAQ(W, u0,u1,u2,u3, QI,QF,QO,QG) do{\
  QI.x=fmaf(W.x,u0,QI.x); QI.y=fmaf(W.x,u1,QI.y); QI.z=fmaf(W.x,u2,QI.z); QI.w=fmaf(W.x,u3,QI.w);\
  QF.x=fmaf(W.y,u0,QF.x); QF.y=fmaf(W.y,u1,QF.y); QF.z=fmaf(W.y,u2,QF.z); QF.w=fmaf(W.y,u3,QF.w);\
  QO.x=fmaf(W.z,u0,QO.x); QO.y=fmaf(W.z,u1,QO.y); QO.z=fmaf(W.z,u2,QO.z); QO.w=fmaf(W.z,u3,QO.w);\
  QG.x=fmaf(W.w,u0,QG.x); QG.y=fmaf(W.w,u1,QG.y); QG.z=fmaf(W.w,u2,QG.z); QG.w=fmaf(W.w,u3,QG.w);\
}while(0)

// One row, 16 columns, all 4 gates. Weights from LDS at WK (+WS per tap).
#define ROW16G(RP, WK, WS, QI0,QI1,QI2,QI3, QF0,QF1,QF2,QF3, QO0,QO1,QO2,QO3, QG0,QG1,QG2,QG3) do{ \
  const float* rp_ = (RP); const float* wk_ = (WK); \
  float4 W0_ = ldf4(wk_); float4 W1_ = ldf4(wk_ + (WS)); float4 W2_ = ldf4(wk_ + 2*(WS)); \
  float m_ = rp_[-1]; \
  float4 A_ = ldf4(rp_); float4 Bq_ = ldf4(rp_+4); float4 Cq_ = ldf4(rp_+8); float4 Dq_ = ldf4(rp_+12); \
  float p_ = rp_[16]; \
  FMAQ(W1_, A_.x,A_.y,A_.z,A_.w,     QI0,QF0,QO0,QG0); \
  FMAQ(W1_, Bq_.x,Bq_.y,Bq_.z,Bq_.w, QI1,QF1,QO1,QG1); \
  FMAQ(W1_, Cq_.x,Cq_.y,Cq_.z,Cq_.w, QI2,QF2,QO2,QG2); \
  FMAQ(W1_, Dq_.x,Dq_.y,Dq_.z,Dq_.w, QI3,QF3,QO3,QG3); \
  FMAQ(W0_, m_,A_.x,A_.y,A_.z,       QI0,QF0,QO0,QG0); \
  FMAQ(W0_, A_.w,Bq_.x,Bq_.y,Bq_.z,  QI1,QF1,QO1,QG1); \
  FMAQ(W0_, Bq_.w,Cq_.x,Cq_.y,Cq_.z, QI2,QF2,QO2,QG2); \
  FMAQ(W0_, Cq_.w,Dq_.x,Dq_.y,Dq_.z, QI3,QF3,QO3,QG3); \
  FMAQ(W2_, A_.y,A_.z,A_.w,Bq_.x,    QI0,QF0,QO0,QG0); \
  FMAQ(W2_, Bq_.y,Bq_.z,Bq_.w,Cq_.x, QI1,QF1,QO1,QG1); \
  FMAQ(W2_, Cq_.y,Cq_.z,Cq_.w,Dq_.x, QI2,QF2,QO2,QG2); \
  FMAQ(W2_, Dq_.y,Dq_.z,Dq_.w,p_,    QI3,QF3,QO3,QG3); \
}while(0)

// One row, 8 columns, all 4 gates.
#define ROW8G(RP, WK, WS, QI0,QI1, QF0,QF1, QO0,QO1, QG0,QG1) do{ \
  const float* rp_ = (RP); const float* wk_ = (WK); \
  float4 W0_ = ldf4(wk_); float4 W1_ = ldf4(wk_ + (WS)); float4 W2_ = ldf4(wk_ + 2*(WS)); \
  float m_ = rp_[-1]; \
  float4 A_ = ldf4(rp_); float4 Bq_ = ldf4(rp_+4); \
  float p_ = rp_[8]; \
  FMAQ(W1_, A_.x,A_.y,A_.z,A_.w,     QI0,QF0,QO0,QG0); \
  FMAQ(W1_, Bq_.x,Bq_.y,Bq_.z,Bq_.w, QI1,QF1,QO1,QG1); \
  FMAQ(W0_, m_,A_.x,A_.y,A_.z,       QI0,QF0,QO0,QG0); \
  FMAQ(W0_, A_.w,Bq_.x,Bq_.y,Bq_.z,  QI1,QF1,QO1,QG1); \
  FMAQ(W2_, A_.y,A_.z,A_.w,Bq_.x,    QI0,QF0,QO0,QG0); \
  FMAQ(W2_, Bq_.y,Bq_.z,Bq_.w,p_,    QI1,QF1,QO1,QG1); \
}while(0)

// ---------------------------------------------------------------------------
// Helpers for dec1k / xconv1 / fallbacks (unchanged from r7)
// ---------------------------------------------------------------------------
__device__ __forceinline__ void fma4v(float w, float u0,float u1,float u2,float u3, float4& a){
    a.x = fmaf(w,u0,a.x); a.y = fmaf(w,u1,a.y);
    a.z = fmaf(w,u2,a.z); a.w = fmaf(w,u3,a.w);
}
__device__ __forceinline__ void fma2v(float w, float u0,float u1, float2& a){
    a.x = fmaf(w,u0,a.x); a.y = fmaf(w,u1,a.y);
}
template<int ROWS>
__device__ __forceinline__ void rowacc4(const float* __restrict__ rowp,
                                        const float* __restrict__ wk,
                                        float4& ai, float4& af, float4& ao, float4& ag)
{
    float  m = rowp[-1];
    float4 a = ldf4(rowp);
    float  p = rowp[4];
    float4 wa = ldf4(wk);
    float4 wb = ldf4(wk + ROWS);
    float4 wc = ldf4(wk + 2*ROWS);
    fma4v(wa.x, m,a.x,a.y,a.z, ai);  fma4v(wa.y, m,a.x,a.y,a.z, af);
    fma4v(wa.z, m,a.x,a.y,a.z, ao);  fma4v(wa.w, m,a.x,a.y,a.z, ag);
    fma4v(wb.x, a.x,a.y,a.z,a.w, ai); fma4v(wb.y, a.x,a.y,a.z,a.w, af);
    fma4v(wb.z, a.x,a.y,a.z,a.w, ao); fma4v(wb.w, a.x,a.y,a.z,a.w, ag);
    fma4v(wc.x, a.y,a.z,a.w,p, ai);  fma4v(wc.y, a.y,a.z,a.w,p, af);
    fma4v(wc.z, a.y,a.z,a.w,p, ao);  fma4v(wc.w, a.y,a.z,a.w,p, ag);
}
template<int ROWS>
__device__ __forceinline__ void rowacc2(const float* __restrict__ rowp,
                                        const float* __restrict__ wk,
                                        float2& ai, float2& af, float2& ao, float2& ag)
{
    float  m = rowp[-1];
    float2 a = *reinterpret_cast<const float2*>(rowp);
    float  p = rowp[2];
    float4 wa = ldf4(wk);
    float4 wb = ldf4(wk + ROWS);
    float4 wc = ldf4(wk + 2*ROWS);
    fma2v(wa.x, m,a.x, ai); fma2v(wa.y, m,a.x, af);
    fma2v(wa.z, m,a.x, ao); fma2v(wa.w, m,a.x, ag);
    fma2v(wb.x, a.x,a.y, ai); fma2v(wb.y, a.x,a.y, af);
    fma2v(wb.z, a.x,a.y, ao); fma2v(wb.w, a.x,a.y, ag);
    fma2v(wc.x, a.y,p, ai); fma2v(wc.y, a.y,p, af);
    fma2v(wc.z, a.y,p, ao); fma2v(wc.w, a.y,p, ag);
}

// ---------------------------------------------------------------------------
// Encoder. 256 threads, FT=16 (L1) / FT=8 (L0), 3 barriers/step.
// hbuf rows: 0 = x; 1..16 = h0 buf0; 17..32 = h0 buf1; 33..64 = h1.
// Phases: P1a: all acc L0(t+1) (kg0 rows x+0..7 -> writes zsA; kg1 rows 8..15 keeps)
//         P1b: kg1 combines L0 -> h0[nxt]; both acc L1(t) (kg0 rows 0..25, kg1 26..47 -> zsB)
//         P2:  kg0 combines L1 -> h1 + seq.
// ---------------------------------------------------------------------------
__global__ __launch_bounds__(256, 1) void enc_kernel(
    const float* __restrict__ x,
    const float* __restrict__ w0, const float* __restrict__ b0,
    const float* __restrict__ w1, const float* __restrict__ b1,
    float* __restrict__ seq,
    float* __restrict__ h1f, float* __restrict__ c1f,
    float* __restrict__ h2f, float* __restrict__ c2f)
{
    __shared__ float wl0[51 * 64];        // (ci*3+d)*64 + ch*4+g, ci<17
    __shared__ float wl1[144 * 128];      // (ci*3+d)*128 + ch*4+g, ci<48
    __shared__ float hbuf[65 * RS];
    __shared__ float zsA[4 * 16 * ZS1];   // L0 partial (kg0)
    __shared__ float zsB[4 * 32 * ZS1];   // L1 partial (kg1)
    __shared__ float cb0[16 * ZS1];       // L0 cell

    const int tid = threadIdx.x;
    const int b = blockIdx.x;
    const int kg = tid >> 7;              // wave-uniform (waves 0,1 vs 2,3)
    const int rB = tid & 127;
    const int chB = rB >> 2, fqB = (rB & 3) * 16;   // L1 lane
    const int chA = rB >> 3, f0A = (rB & 7) * 8;    // L0 lane
    const int xl = tid - 192;             // wave 3 stages x

    for (int idx = tid; idx < 51 * 64; idx += 256) {
        int k = idx >> 6, rr = idx & 63;
        int ch = rr >> 2, g = rr & 3;
        int ci = k / 3, d = k - ci * 3;
        wl0[idx] = w0[((g * 16 + ch) * 17 + ci) * 9 + d * 3 + 1];
    }
    for (int idx = tid; idx < 144 * 128; idx += 256) {
        int k = idx >> 7, rr = idx & 127;
        int ch = rr >> 2, g = rr & 3;
        int ci = k / 3, d = k - ci * 3;
        wl1[idx] = w1[((g * 32 + ch) * 48 + ci) * 9 + d * 3 + 1];
    }
    for (int i = tid; i < 65 * RS; i += 256) hbuf[i] = 0.f;
    for (int i = tid; i < 16 * ZS1; i += 256) cb0[i] = 0.f;

    const float biA = b0[chA], bfA = b0[16 + chA], boA = b0[32 + chA], bgA = b0[48 + chA];
    const float biB = b1[chB], bfB = b1[32 + chB], boB = b1[64 + chB], bgB = b1[96 + chB];
    __syncthreads();

    // stage x(0)
    if (tid < 64) hbuf[4 + tid] = x[(size_t)b * T_ * 64 + tid];
    __syncthreads();

    const float4 z4 = make_float4(0.f, 0.f, 0.f, 0.f);

    // ---- prologue: h0(0) from x(0) only (h0,h1 zero) ----
    {
        float4 u0=z4,u1=z4,u2=z4,u3=z4,u4=z4,u5=z4,u6=z4,u7=z4;
        if (kg == 0) {
            ROW8G(&hbuf[4 + f0A], &wl0[chA * 4], 64, u0,u1,u2,u3,u4,u5,u6,u7);
            float* zp;
            zp = &zsA[(0*16+chA)*ZS1 + f0A]; stf4(zp, u0); stf4(zp+4, u1);
            zp = &zsA[(1*16+chA)*ZS1 + f0A]; stf4(zp, u2); stf4(zp+4, u3);
            zp = &zsA[(2*16+chA)*ZS1 + f0A]; stf4(zp, u4); stf4(zp+4, u5);
            zp = &zsA[(3*16+chA)*ZS1 + f0A]; stf4(zp, u6); stf4(zp+4, u7);
        }
        __syncthreads();
        if (kg == 1) {
            const float* za = &zsA[chA * ZS1 + f0A];
            float4 zi0 = ldf4(za),              zi1 = ldf4(za + 4);
            float4 zf0 = ldf4(za + 16*ZS1),     zf1 = ldf4(za + 16*ZS1 + 4);
            float4 zo0 = ldf4(za + 32*ZS1),     zo1 = ldf4(za + 32*ZS1 + 4);
            float4 zg0 = ldf4(za + 48*ZS1),     zg1 = ldf4(za + 48*ZS1 + 4);
            float4 c0a = z4, c0b = z4;
            float4 h0a = gate4(zi0, zf0, zo0, zg0, biA, bfA, boA, bgA, c0a);
            float4 h0b = gate4(zi1, zf1, zo1, zg1, biA, bfA, boA, bgA, c0b);
            stf4(&cb0[chA * ZS1 + f0A], c0a);
            stf4(&cb0[chA * ZS1 + f0A + 4], c0b);
            stf4(&hbuf[(1 + chA) * RS + 4 + f0A], h0a);
            stf4(&hbuf[(1 + chA) * RS + 4 + f0A + 4], h0b);
            if (xl >= 0 && xl < 64 && T_ > 1)
                hbuf[4 + xl] = x[((size_t)b * T_ + 1) * 64 + xl];   // stage x(1)
        }
        __syncthreads();
    }

    float4 c1q0 = z4, c1q1 = z4, c1q2 = z4, c1q3 = z4;   // L1 cell (kg0 regs)

#pragma unroll 1
    for (int t = 0; t < T_; ++t) {
        const int cur = t & 1, nxt = cur ^ 1;
        const bool doL0 = (t + 1 < T_);

        // ---------- P1a: accumulate L0(t+1) ----------
        float4 u0=z4,u1=z4,u2=z4,u3=z4,u4=z4,u5=z4,u6=z4,u7=z4;
        float xv = 0.f;
        if (kg == 0) {
            if (doL0) {
                ROW8G(&hbuf[4 + f0A], &wl0[chA * 4], 64, u0,u1,u2,u3,u4,u5,u6,u7);
#pragma unroll 1
                for (int j = 0; j < 8; ++j)
                    ROW8G(&hbuf[(1 + cur*16 + j) * RS + 4 + f0A],
                          &wl0[((1 + j) * 3) * 64 + chA * 4], 64,
                          u0,u1,u2,u3,u4,u5,u6,u7);
                float* zp;
                zp = &zsA[(0*16+chA)*ZS1 + f0A]; stf4(zp, u0); stf4(zp+4, u1);
                zp = &zsA[(1*16+chA)*ZS1 + f0A]; stf4(zp, u2); stf4(zp+4, u3);
                zp = &zsA[(2*16+chA)*ZS1 + f0A]; stf4(zp, u4); stf4(zp+4, u5);
                zp = &zsA[(3*16+chA)*ZS1 + f0A]; stf4(zp, u6); stf4(zp+4, u7);
            }
        } else {
            if (doL0) {
#pragma unroll 1
                for (int j = 8; j < 16; ++j)
                    ROW8G(&hbuf[(1 + cur*16 + j) * RS + 4 + f0A],
                          &wl0[((1 + j) * 3) * 64 + chA * 4], 64,
                          u0,u1,u2,u3,u4,u5,u6,u7);
            }
            if (xl >= 0 && xl < 64 && t + 2 < T_)
                xv = x[((size_t)b * T_ + t + 2) * 64 + xl];
        }
        __syncthreads();                                         // Y1

        // ---------- P1b: kg1 combines L0 -> h0[nxt]; both acc L1(t) ----------
        float4 li0=z4,li1=z4,li2=z4,li3=z4, lf0=z4,lf1=z4,lf2=z4,lf3=z4;
        float4 lo0=z4,lo1=z4,lo2=z4,lo3=z4, lg0=z4,lg1=z4,lg2=z4,lg3=z4;
        if (kg == 0) {
#pragma unroll 1
            for (int j = 0; j < 16; ++j)
                ROW16G(&hbuf[(1 + cur*16 + j) * RS + 4 + fqB],
                       &wl1[(j * 3) * 128 + chB * 4], 128,
                       li0,li1,li2,li3, lf0,lf1,lf2,lf3, lo0,lo1,lo2,lo3, lg0,lg1,lg2,lg3);
#pragma unroll 1
            for (int j = 16; j < 26; ++j)
                ROW16G(&hbuf[(17 + j) * RS + 4 + fqB],
                       &wl1[(j * 3) * 128 + chB * 4], 128,
                       li0,li1,li2,li3, lf0,lf1,lf2,lf3, lo0,lo1,lo2,lo3, lg0,lg1,lg2,lg3);
        } else {
            if (doL0) {
                const float* za = &zsA[chA * ZS1 + f0A];
                float4 zi0 = add4(u0, ldf4(za)),          zi1 = add4(u1, ldf4(za + 4));
                float4 zf0 = add4(u2, ldf4(za + 16*ZS1)), zf1 = add4(u3, ldf4(za + 16*ZS1 + 4));
                float4 zo0 = add4(u4, ldf4(za + 32*ZS1)), zo1 = add4(u5, ldf4(za + 32*ZS1 + 4));
                float4 zg0 = add4(u6, ldf4(za + 48*ZS1)), zg1 = add4(u7, ldf4(za + 48*ZS1 + 4));
                float4 c0a = ldf4(&cb0[chA * ZS1 + f0A]);
                float4 c0b = ldf4(&cb0[chA * ZS1 + f0A + 4]);
                float4 h0a = gate4(zi0, zf0, zo0, zg0, biA, bfA, boA, bgA, c0a);
                float4 h0b = gate4(zi1, zf1, zo1, zg1, biA, bfA, boA, bgA, c0b);
                stf4(&cb0[chA * ZS1 + f0A], c0a);
                stf4(&cb0[chA * ZS1 + f0A + 4], c0b);
                stf4(&hbuf[(1 + nxt*16 + chA) * RS + 4 + f0A], h0a);
                stf4(&hbuf[(1 + nxt*16 + chA) * RS + 4 + f0A + 4], h0b);
            }
            if (xl >= 0 && xl < 64 && t + 2 < T_)
                hbuf[4 + xl] = xv;                               // stage x(t+2)
#pragma unroll 1
            for (int j = 26; j < 48; ++j)
                ROW16G(&hbuf[(17 + j) * RS + 4 + fqB],
                       &wl1[(j * 3) * 128 + chB * 4], 128,
                       li0,li1,li2,li3, lf0,lf1,lf2,lf3, lo0,lo1,lo2,lo3, lg0,lg1,lg2,lg3);
            float* zp = &zsB[chB * ZS1 + fqB];
            stf4(zp, li0); stf4(zp+4, li1); stf4(zp+8, li2); stf4(zp+12, li3);
            zp += 32*ZS1; stf4(zp, lf0); stf4(zp+4, lf1); stf4(zp+8, lf2); stf4(zp+12, lf3);
            zp += 32*ZS1; stf4(zp, lo0); stf4(zp+4, lo1); stf4(zp+8, lo2); stf4(zp+12, lo3);
            zp += 32*ZS1; stf4(zp, lg0); stf4(zp+4, lg1); stf4(zp+8, lg2); stf4(zp+12, lg3);
        }
        __syncthreads();                                         // Y2

        // ---------- P2: kg0 combines L1 -> h1 + seq ----------
        if (kg == 0) {
            const float* zb = &zsB[chB * ZS1 + fqB];
            float4 zi0 = add4(li0, ldf4(zb));      float4 zi1 = add4(li1, ldf4(zb+4));
            float4 zi2 = add4(li2, ldf4(zb+8));    float4 zi3 = add4(li3, ldf4(zb+12));
            zb += 32*ZS1;
            float4 zf0 = add4(lf0, ldf4(zb));      float4 zf1 = add4(lf1, ldf4(zb+4));
            float4 zf2 = add4(lf2, ldf4(zb+8));    float4 zf3 = add4(lf3, ldf4(zb+12));
            zb += 32*ZS1;
            float4 zo0 = add4(lo0, ldf4(zb));      float4 zo1 = add4(lo1, ldf4(zb+4));
            float4 zo2 = add4(lo2, ldf4(zb+8));    float4 zo3 = add4(lo3, ldf4(zb+12));
            zb += 32*ZS1;
            float4 zg0 = add4(lg0, ldf4(zb));      float4 zg1 = add4(lg1, ldf4(zb+4));
            float4 zg2 = add4(lg2, ldf4(zb+8));    float4 zg3 = add4(lg3, ldf4(zb+12));
            float4 h0q = gate4(zi0, zf0, zo0, zg0, biB, bfB, boB, bgB, c1q0);
            float4 h1q = gate4(zi1, zf1, zo1, zg1, biB, bfB, boB, bgB, c1q1);
            float4 h2q = gate4(zi2, zf2, zo2, zg2, biB, bfB, boB, bgB, c1q2);
            float4 h3q = gate4(zi3, zf3, zo3, zg3, biB, bfB, boB, bgB, c1q3);
            float* hrow = &hbuf[(33 + chB) * RS + 4 + fqB];
            stf4(hrow, h0q); stf4(hrow+4, h1q); stf4(hrow+8, h2q); stf4(hrow+12, h3q);
            float* sp = &seq[((size_t)t * B_ + b) * 2048 + chB * 64 + fqB];
            stf4(sp, h0q); stf4(sp+4, h1q); stf4(sp+8, h2q); stf4(sp+12, h3q);
        }
        __syncthreads();                                         // Z
    }

    // final states
    const int curF = (T_ - 1) & 1;
    for (int i = tid; i < 1024; i += 256) {
        int ch = i >> 6, f = i & 63;
        h1f[b * 1024 + i] = hbuf[(1 + curF*16 + ch) * RS + 4 + f];
        c1f[b * 1024 + i] = cb0[ch * ZS1 + f];
    }
    if (kg == 0) {
        const float* hrow = &hbuf[(33 + chB) * RS + 4 + fqB];
        float* hp2 = &h2f[b * 2048 + chB * 64 + fqB];
        stf4(hp2, ldf4(hrow)); stf4(hp2+4, ldf4(hrow+4));
        stf4(hp2+8, ldf4(hrow+8)); stf4(hp2+12, ldf4(hrow+12));
        float* cp2 = &c2f[b * 2048 + chB * 64 + fqB];
        stf4(cp2, c1q0); stf4(cp2+4, c1q1); stf4(cp2+8, c1q2); stf4(cp2+12, c1q3);
    }
}

// ---------------------------------------------------------------------------
// xconv0: x-part pre-activations for dec0. 256 thr, 2 timesteps/block, FT=16.
// ---------------------------------------------------------------------------
__global__ __launch_bounds__(256, 2) void xconv0_kernel(
    const float* __restrict__ seqIn, const float* __restrict__ w,
    float* __restrict__ zx, int t0)
{
    __shared__ float wl[96 * 128];        // x rows (w rows 0..31)
    __shared__ float xt[2][32 * RS];

    const int tid = threadIdx.x;
    const int p  = blockIdx.x / B_;
    const int b  = blockIdx.x - p * B_;
    const int h  = tid >> 7;
    const int rB = tid & 127;
    const int ch = rB >> 2, fq = (rB & 3) * 16;
    const int tl = 2 * p + h;
    const int t  = t0 + tl;

    for (int idx = tid; idx < 96 * 128; idx += 256) {
        int k = idx >> 7, rr = idx & 127;
        int c8 = rr >> 2, g = rr & 3;
        int ci = k / 3, d = k - ci * 3;
        wl[idx] = w[((g * 32 + c8) * 64 + ci) * 9 + d * 3 + 1];
    }
    for (int i = rB; i < 32 * 8; i += 128) {         // zero pads
        int row = i >> 3, c = i & 7;
        xt[h][row * RS + (c < 4 ? c : 64 + c)] = 0.f;
    }
    {   // stage this half's seq(t): 16 floats/thread
        const float* s = &seqIn[((size_t)t * B_ + b) * 2048 + rB * 16];
        float4 v0 = ldf4(s), v1 = ldf4(s+4), v2 = ldf4(s+8), v3 = ldf4(s+12);
        float* d = &xt[h][(rB >> 2) * RS + 4 + (rB & 3) * 16];
        stf4(d, v0); stf4(d+4, v1); stf4(d+8, v2); stf4(d+12, v3);
    }
    __syncthreads();

    const float4 z4 = make_float4(0.f,0.f,0.f,0.f);
    float4 li0=z4,li1=z4,li2=z4,li3=z4, lf0=z4,lf1=z4,lf2=z4,lf3=z4;
    float4 lo0=z4,lo1=z4,lo2=z4,lo3=z4, lg0=z4,lg1=z4,lg2=z4,lg3=z4;
#pragma unroll 1
    for (int rr = 0; rr < 32; ++rr)
        ROW16G(&xt[h][rr * RS + 4 + fq], &wl[(rr * 3) * 128 + ch * 4], 128,
               li0,li1,li2,li3, lf0,lf1,lf2,lf3, lo0,lo1,lo2,lo3, lg0,lg1,lg2,lg3);

    float* zp = &zx[(((size_t)tl * B_ + b) * 4) * 2048 + ch * 64 + fq];
    stf4(zp, li0); stf4(zp+4, li1); stf4(zp+8, li2); stf4(zp+12, li3);
    zp += 2048; stf4(zp, lf0); stf4(zp+4, lf1); stf4(zp+8, lf2); stf4(zp+12, lf3);
    zp += 2048; stf4(zp, lo0); stf4(zp+4, lo1); stf4(zp+8, lo2); stf4(zp+12, lo3);
    zp += 2048; stf4(zp, lg0); stf4(zp+4, lg1); stf4(zp+8, lg2); stf4(zp+12, lg3);
}

// ---------------------------------------------------------------------------
// xconv1: x-part for dec1 (32 -> 16ch). One block per (t,b). (r7, unchanged)
// ---------------------------------------------------------------------------
__global__ __launch_bounds__(256, 2) void xconv1_kernel(
    const float* __restrict__ seqIn, const float* __restrict__ w,
    float* __restrict__ zx, int t0)
{
    __shared__ float wl[96 * 64];
    __shared__ float xt[32 * RS];

    const int tid = threadIdx.x;
    const int tl = blockIdx.x / B_;
    const int b  = blockIdx.x - tl * B_;
    const int t  = t0 + tl;

    for (int idx = tid; idx < 96 * 64; idx += 256) {
        int k = idx >> 6, rr = idx & 63;
        int ch = rr >> 2, g = rr & 3;
        int ci = k / 3, d = k - ci * 3;
        wl[idx] = w[((g * 16 + ch) * 48 + ci) * 9 + d * 3 + 1];
    }
    {
        int rr = tid >> 3, j = tid & 7;
        xt[rr * RS + (j < 4 ? j : 64 + j)] = 0.f;
    }
    {
        const float* s = &seqIn[((size_t)t * B_ + b) * 2048 + tid * 8];
        float4 v0 = ldf4(s);
        float4 v1 = ldf4(s + 4);
        int ci = tid >> 3, col = (tid & 7) * 8;
        stf4(&xt[ci * RS + 4 + col], v0);
        stf4(&xt[ci * RS + 4 + col + 4], v1);
    }
    __syncthreads();

    const int ch = tid >> 4, f0 = (tid & 15) * 4;
    const float4 z4 = make_float4(0.f,0.f,0.f,0.f);
    float4 ai=z4, af=z4, ao=z4, ag=z4;
#pragma unroll 1
    for (int rr = 0; rr < 32; ++rr)
        rowacc4<64>(&xt[rr * RS + 4 + f0], wl + (rr * 3) * 64 + ch * 4, ai, af, ao, ag);

    float* zp = &zx[(((size_t)tl * B_ + b) * 4) * 1024 + ch * 64 + f0];
    stf4(zp, ai);
    stf4(zp + 1024, af);
    stf4(zp + 2048, ao);
    stf4(zp + 3072, ag);
}

// ---------------------------------------------------------------------------
// dec0k: decoder L0 h-recurrence. 256 thr, FT=16, kg=2, 2 barriers/step.
// x-part read from zx in P2 (no reg prefetch: keeps VGPR ~110).
// ---------------------------------------------------------------------------
__global__ __launch_bounds__(256, 1) void dec0k(
    const float* __restrict__ w, const float* __restrict__ bias,
    float* __restrict__ seq, const float* __restrict__ zx,
    const float* __restrict__ hin, const float* __restrict__ cin,
    float* __restrict__ hout, float* __restrict__ cout,
    int t0, int tn)
{
    __shared__ float wl[96 * 128];        // h rows (w rows 32..63)
    __shared__ float hp[32 * RS];
    __shared__ float zs[4 * 32 * ZS1];

    const int tid = threadIdx.x, b = blockIdx.x;
    const int kg = tid >> 7;
    const int rB = tid & 127;
    const int ch = rB >> 2, fq = (rB & 3) * 16;

    for (int idx = tid; idx < 96 * 128; idx += 256) {
        int k = idx >> 7, rr = idx & 127;
        int c8 = rr >> 2, g = rr & 3;
        int ci = k / 3, d = k - ci * 3;
        wl[idx] = w[((g * 32 + c8) * 64 + 32 + ci) * 9 + d * 3 + 1];
    }
    for (int i = tid; i < 32 * RS; i += 256) hp[i] = 0.f;
    const float bi = bias[ch], bf = bias[32 + ch], bo = bias[64 + ch], bg = bias[96 + ch];
    __syncthreads();
    for (int i = tid; i < 2048; i += 256) {
        int c8 = i >> 6, f = i & 63;
        hp[c8 * RS + 4 + f] = hin[b * 2048 + i];
    }
    const float4 z4 = make_float4(0.f, 0.f, 0.f, 0.f);
    float4 ca0 = z4, ca1 = z4, ca2 = z4, ca3 = z4;
    if (kg == 0) {
        const float* cp = &cin[b * 2048 + ch * 64 + fq];
        ca0 = ldf4(cp); ca1 = ldf4(cp+4); ca2 = ldf4(cp+8); ca3 = ldf4(cp+12);
    }
    __syncthreads();

#pragma unroll 1
    for (int tl = 0; tl < tn; ++tl) {
        const int t = t0 + tl;
        float4 li0=z4,li1=z4,li2=z4,li3=z4, lf0=z4,lf1=z4,lf2=z4,lf3=z4;
        float4 lo0=z4,lo1=z4,lo2=z4,lo3=z4, lg0=z4,lg1=z4,lg2=z4,lg3=z4;
#pragma unroll 1
        for (int j = 0; j < 16; ++j) {
            const int ci = kg * 16 + j;
            ROW16G(&hp[ci * RS + 4 + fq], &wl[(ci * 3) * 128 + ch * 4], 128,
                   li0,li1,li2,li3, lf0,lf1,lf2,lf3, lo0,lo1,lo2,lo3, lg0,lg1,lg2,lg3);
        }
        if (kg == 1) {
            float* zp = &zs[ch * ZS1 + fq];
            stf4(zp, li0); stf4(zp+4, li1); stf4(zp+8, li2); stf4(zp+12, li3);
            zp += 32*ZS1; stf4(zp, lf0); stf4(zp+4, lf1); stf4(zp+8, lf2); stf4(zp+12, lf3);
            zp += 32*ZS1; stf4(zp, lo0); stf4(zp+4, lo1); stf4(zp+8, lo2); stf4(zp+12, lo3);
            zp += 32*ZS1; stf4(zp, lg0); stf4(zp+4, lg1); stf4(zp+8, lg2); stf4(zp+12, lg3);
        }
        __syncthreads();                                         // Y
        if (kg == 0) {
            const float* xz = &zx[((size_t)tl * B_ + b) * 8192 + ch * 64 + fq];
            const float* zp = &zs[ch * ZS1 + fq];
            float4 zi0 = add4(add4(li0, ldf4(zp)),    ldf4(xz));
            float4 zi1 = add4(add4(li1, ldf4(zp+4)),  ldf4(xz+4));
            float4 zi2 = add4(add4(li2, ldf4(zp+8)),  ldf4(xz+8));
            float4 zi3 = add4(add4(li3, ldf4(zp+12)), ldf4(xz+12));
            zp += 32*ZS1; xz += 2048;
            float4 zf0 = add4(add4(lf0, ldf4(zp)),    ldf4(xz));
            float4 zf1 = add4(add4(lf1, ldf4(zp+4)),  ldf4(xz+4));
            float4 zf2 = add4(add4(lf2, ldf4(zp+8)),  ldf4(xz+8));
            float4 zf3 = add4(add4(lf3, ldf4(zp+12)), ldf4(xz+12));
            zp += 32*ZS1; xz += 2048;
            float4 zo0 = add4(add4(lo0, ldf4(zp)),    ldf4(xz));
            float4 zo1 = add4(add4(lo1, ldf4(zp+4)),  ldf4(xz+4));
            float4 zo2 = add4(add4(lo2, ldf4(zp+8)),  ldf4(xz+8));
            float4 zo3 = add4(add4(lo3, ldf4(zp+12)), ldf4(xz+12));
            zp += 32*ZS1; xz += 2048;
            float4 zg0 = add4(add4(lg0, ldf4(zp)),    ldf4(xz));
            float4 zg1 = add4(add4(lg1, ldf4(zp+4)),  ldf4(xz+4));
            float4 zg2 = add4(add4(lg2, ldf4(zp+8)),  ldf4(xz+8));
            float4 zg3 = add4(add4(lg3, ldf4(zp+12)), ldf4(xz+12));
            float4 h0q = gate4(zi0, zf0, zo0, zg0, bi, bf, bo, bg, ca0);
            float4 h1q = gate4(zi1, zf1, zo1, zg1, bi, bf, bo, bg, ca1);
            float4 h2q = gate4(zi2, zf2, zo2, zg2, bi, bf, bo, bg, ca2);
            float4 h3q = gate4(zi3, zf3, zo3, zg3, bi, bf, bo, bg, ca3);
            float* hrow = &hp[ch * RS + 4 + fq];
            stf4(hrow, h0q); stf4(hrow+4, h1q); stf4(hrow+8, h2q); stf4(hrow+12, h3q);
            float* sp = &seq[((size_t)t * B_ + b) * 2048 + ch * 64 + fq];
            stf4(sp, h0q); stf4(sp+4, h1q); stf4(sp+8, h2q); stf4(sp+12, h3q);
        }
        __syncthreads();                                         // Z
    }

    for (int i = tid; i < 2048; i += 256) {
        int c8 = i >> 6, f = i & 63;
        hout[b * 2048 + i] = hp[c8 * RS + 4 + f];
    }
    if (kg == 0) {
        float* cp = &cout[b * 2048 + ch * 64 + fq];
        stf4(cp, ca0); stf4(cp+4, ca1); stf4(cp+8, ca2); stf4(cp+12, ca3);
    }
}

// ---------------------------------------------------------------------------
// dec1k: decoder L1 h-recurrence + final 1x1 conv. (r7, unchanged: 512 thr)
// ---------------------------------------------------------------------------
__global__ __launch_bounds__(512, 1) void dec1k(
    const float* __restrict__ w, const float* __restrict__ bias,
    const float* __restrict__ zx,
    const float* __restrict__ hin, const float* __restrict__ cin,
    float* __restrict__ hout, float* __restrict__ cout,
    const float* __restrict__ fw, const float* __restrict__ fb,
    float* __restrict__ out, int t0, int tn)
{
    __shared__ float wl[48 * 64];
    __shared__ float hp[16 * RS];
    __shared__ float zs[4 * 16 * ZS1];
    __shared__ float bs[64];
    __shared__ float fcw[16];
    __shared__ float fcb;

    const int tid = threadIdx.x, b = blockIdx.x;
    const int kg = tid >> 8, r = tid & 255;
    const int ch = r >> 4, f0 = (r & 15) * 4;

    for (int idx = tid; idx < 48 * 64; idx += 512) {
        int k = idx >> 6, rr = idx & 63;
        int c8 = rr >> 2, g = rr & 3;
        int ci = k / 3, d = k - ci * 3;
        wl[idx] = w[((g * 16 + c8) * 48 + 32 + ci) * 9 + d * 3 + 1];
    }
    if (tid < 64) bs[tid] = bias[tid];
    if (tid < 16) fcw[tid] = fw[tid];
    if (tid == 16) fcb = fb[0];
    for (int i = tid; i < 16 * RS; i += 512) hp[i] = 0.f;
    __syncthreads();
    for (int i = tid; i < 1024; i += 512) {
        int c8 = i >> 6, f = i & 63;
        hp[c8 * RS + 4 + f] = hin[b * 1024 + i];
    }
    const float bi = bs[ch], bf = bs[16 + ch], bo = bs[32 + ch], bg = bs[48 + ch];
    const float4 z4 = make_float4(0.f, 0.f, 0.f, 0.f);
    float4 cc = z4;
    if (kg == 0) cc = ldf4(&cin[b * 1024 + ch * 64 + f0]);
    const float fcbv = fcb;
    __syncthreads();

#pragma unroll 1
    for (int tl = 0; tl < tn; ++tl) {
        const int t = t0 + tl;
        if (tid < 64 && t > 0) {
            float a = fcbv;
#pragma unroll
            for (int k2 = 0; k2 < 16; ++k2)
                a = fmaf(fcw[k2], hp[k2 * RS + 4 + tid], a);
            out[(b * T_ + (t - 1)) * 64 + tid] = a;
        }
        float4 xi=z4, xf=z4, xo=z4, xg=z4;
        if (kg == 0) {
            const float* zp0 = &zx[((size_t)tl * B_ + b) * 4096 + ch * 64 + f0];
            xi = ldf4(zp0);
            xf = ldf4(zp0 + 1024);
            xo = ldf4(zp0 + 2048);
            xg = ldf4(zp0 + 3072);
        }
        float4 ai = z4, af = z4, ao = z4, ag = z4;
#pragma unroll 1
        for (int j = 0; j < 8; ++j) {
            const int ci = kg * 8 + j;
            rowacc4<64>(&hp[ci * RS + 4 + f0], &wl[(ci * 3) * 64 + ch * 4],
                        ai, af, ao, ag);
        }
        if (kg == 1) {
            stf4(&zs[(0*16+ch)*ZS1 + f0], ai);
            stf4(&zs[(1*16+ch)*ZS1 + f0], af);
            stf4(&zs[(2*16+ch)*ZS1 + f0], ao);
            stf4(&zs[(3*16+ch)*ZS1 + f0], ag);
        }
        __syncthreads();
        if (kg == 0) {
            float4 zi = add4(add4(ai, xi), ldf4(&zs[(0*16+ch)*ZS1 + f0]));
            float4 zf = add4(add4(af, xf), ldf4(&zs[(1*16+ch)*ZS1 + f0]));
            float4 zo = add4(add4(ao, xo), ldf4(&zs[(2*16+ch)*ZS1 + f0]));
            float4 zg = add4(add4(ag, xg), ldf4(&zs[(3*16+ch)*ZS1 + f0]));
            float4 hq = gate4(zi, zf, zo, zg, bi, bf, bo, bg, cc);
            stf4(&hp[ch * RS + 4 + f0], hq);
        }
        __syncthreads();
    }

    if (tid < 64) {
        float a = fcbv;
#pragma unroll
        for (int k2 = 0; k2 < 16; ++k2)
            a = fmaf(fcw[k2], hp[k2 * RS + 4 + tid], a);
        out[(b * T_ + (t0 + tn - 1)) * 64 + tid] = a;
    }
    for (int i = tid; i < 1024; i += 512) {
        int c8 = i >> 6, f = i & 63;
        hout[b * 1024 + i] = hp[c8 * RS + 4 + f];
    }
    if (kg == 0) stf4(&cout[b * 1024 + ch * 64 + f0], cc);
}

// ---------------------------------------------------------------------------
// Fallbacks (ws too small for zx): fused x+h decoders (r7, unchanged).
// ---------------------------------------------------------------------------
__global__ __launch_bounds__(512, 1) void dec0_fb(
    const float* __restrict__ w, const float* __restrict__ bias,
    float* __restrict__ seq,
    const float* __restrict__ hin, const float* __restrict__ cin)
{
    __shared__ float wl[192 * 128];
    __shared__ float bs[128];
    __shared__ float xin[32 * RS];
    __shared__ float hp[32 * RS];

    const int tid = threadIdx.x;
    const int b = blockIdx.x;

    for (int idx = tid; idx < 192 * 128; idx += 512) {
        int k = idx >> 7, rr = idx & 127;
        int ch = rr >> 2, g = rr & 3;
        int ci = k / 3, d = k - ci * 3;
        wl[idx] = w[((g * 32 + ch) * 64 + ci) * 9 + d * 3 + 1];
    }
    if (tid < 128) bs[tid] = bias[tid];
    for (int i = tid; i < 32 * RS; i += 512) { xin[i] = 0.f; hp[i] = 0.f; }
    __syncthreads();
    {
        const float* hs = &hin[b * 2048 + tid * 4];
        float4 hv = ldf4(hs);
        int ci = tid >> 4, col = (tid & 15) * 4;
        stf4(&hp[ci * RS + 4 + col], hv);
    }
    const int ch = tid >> 4, f0 = (tid & 15) * 4;
    float4 cc = ldf4(&cin[b * 2048 + ch * 64 + f0]);
    const float bi = bs[ch], bf = bs[32 + ch], bo = bs[64 + ch], bg = bs[96 + ch];
    const float4 z4 = make_float4(0.f,0.f,0.f,0.f);

    float4 nx = ldf4(&seq[(size_t)b * 2048 + tid * 4]);

#pragma unroll 1
    for (int t = 0; t < T_; ++t) {
        {
            int ci = tid >> 4, col = (tid & 15) * 4;
            stf4(&xin[ci * RS + 4 + col], nx);
        }
        __syncthreads();
        if (t + 1 < T_)
            nx = ldf4(&seq[((size_t)(t + 1) * B_ + b) * 2048 + tid * 4]);
        float4 ai = z4, af = z4, ao = z4, ag = z4;
#pragma unroll 1
        for (int rr = 0; rr < 32; ++rr)
            rowacc4<128>(&xin[rr * RS + 4 + f0], wl + (rr * 3) * 128 + ch * 4, ai, af, ao, ag);
#pragma unroll 1
        for (int rr = 0; rr < 32; ++rr)
            rowacc4<128>(&hp[rr * RS + 4 + f0], wl + ((32 + rr) * 3) * 128 + ch * 4, ai, af, ao, ag);
        float4 hn = gate4(ai, af, ao, ag, bi, bf, bo, bg, cc);
        __syncthreads();
        stf4(&hp[ch * RS + 4 + f0], hn);
        stf4(&seq[((size_t)t * B_ + b) * 2048 + ch * 64 + f0], hn);
    }
}

__global__ __launch_bounds__(512, 1) void dec1_fb(
    const float* __restrict__ w, const float* __restrict__ bias,
    const float* __restrict__ seq,
    const float* __restrict__ hin, const float* __restrict__ cin,
    const float* __restrict__ fw, const float* __restrict__ fb,
    float* __restrict__ out)
{
    __shared__ float wl[144 * 64];
    __shared__ float bs[64];
    __shared__ float xin[32 * RS];
    __shared__ float hp[16 * RS];
    __shared__ float fcw[16];
    __shared__ float fcb;

    const int tid = threadIdx.x;
    const int b = blockIdx.x;

    for (int idx = tid; idx < 144 * 64; idx += 512) {
        int k = idx >> 6, rr = idx & 63;
        int ch = rr >> 2, g = rr & 3;
        int ci = k / 3, d = k - ci * 3;
        wl[idx] = w[((g * 16 + ch) * 48 + ci) * 9 + d * 3 + 1];
    }
    if (tid < 64) bs[tid] = bias[tid];
    if (tid < 16) fcw[tid] = fw[tid];
    if (tid == 16) fcb = fb[0];
    for (int i = tid; i < 32 * RS; i += 512) xin[i] = 0.f;
    for (int i = tid; i < 16 * RS; i += 512) hp[i] = 0.f;
    __syncthreads();
    {
        const float* hs = &hin[b * 1024 + tid * 2];
        float2 hv = *reinterpret_cast<const float2*>(hs);
        int ci = tid >> 5, col = (tid & 31) * 2;
        *reinterpret_cast<float2*>(&hp[ci * RS + 4 + col]) = hv;
    }
    const int ch = tid >> 5, f0 = (tid & 31) * 2;
    float2 cc = *reinterpret_cast<const float2*>(&cin[b * 1024 + ch * 64 + f0]);
    const float bi = bs[ch], bf = bs[16 + ch], bo = bs[32 + ch], bg = bs[48 + ch];
    const float2 z2 = make_float2(0.f,0.f);
    float4 nx = ldf4(&seq[(size_t)b * 2048 + tid * 4]);
    __syncthreads();

#pragma unroll 1
    for (int t = 0; t < T_; ++t) {
        {
            int ci = tid >> 4, col = (tid & 15) * 4;
            stf4(&xin[ci * RS + 4 + col], nx);
        }
        __syncthreads();
        if (t + 1 < T_)
            nx = ldf4(&seq[((size_t)(t + 1) * B_ + b) * 2048 + tid * 4]);

        float2 ai = z2, af = z2, ao = z2, ag = z2;
#pragma unroll 1
        for (int rr = 0; rr < 32; ++rr)
            rowacc2<64>(&xin[rr * RS + 4 + f0], wl + (rr * 3) * 64 + ch * 4, ai, af, ao, ag);
#pragma unroll 1
        for (int rr = 0; rr < 16; ++rr)
            rowacc2<64>(&hp[rr * RS + 4 + f0], wl + ((32 + rr) * 3) * 64 + ch * 4, ai, af, ao, ag);

        float2 hh;
        hh.x = gate1(ai.x + bi, af.x + bf, ao.x + bo, ag.x + bg, cc.x);
        hh.y = gate1(ai.y + bi, af.y + bf, ao.y + bo, ag.y + bg, cc.y);
        __syncthreads();
        *reinterpret_cast<float2*>(&hp[ch * RS + 4 + f0]) = hh;
        __syncthreads();

        if (tid < 64) {
            float a = fcb;
#pragma unroll
            for (int k2 = 0; k2 < 16; ++k2)
                a = fmaf(fcw[k2], hp[k2 * RS + 4 + tid], a);
            out[(b * T_ + t) * 64 + tid] = a;
        }
    }
}

// ---------------------------------------------------------------------------
extern "C" void kernel_launch(void* const* d_in, const int* in_sizes, int n_in,
                              void* d_out, int out_size, void* d_ws, size_t ws_size,
                              hipStream_t stream)
{
    (void)in_sizes; (void)n_in; (void)out_size;
    const float* x   = (const float*)d_in[0];
    const float* ew0 = (const float*)d_in[1];
    const float* eb0 = (const float*)d_in[2];
    const float* ew1 = (const float*)d_in[3];
    const float* eb1 = (const float*)d_in[4];
    const float* dw0 = (const float*)d_in[5];
    const float* db0 = (const float*)d_in[6];
    const float* dw1 = (const float*)d_in[7];
    const float* db1 = (const float*)d_in[8];
    const float* fw  = (const float*)d_in[9];
    const float* fb  = (const float*)d_in[10];
    float* out = (float*)d_out;

    float* ws  = (float*)d_ws;
    size_t off = 0;
    float* seq = ws + off; off += (size_t)T_ * B_ * 2048;
    float* h1f = ws + off; off += (size_t)B_ * 1024;
    float* c1f = ws + off; off += (size_t)B_ * 1024;
    float* h2f = ws + off; off += (size_t)B_ * 2048;
    float* c2f = ws + off; off += (size_t)B_ * 2048;
    float* hd0 = ws + off; off += (size_t)B_ * 2048;
    float* cd0 = ws + off; off += (size_t)B_ * 2048;
    float* hd1 = ws + off; off += (size_t)B_ * 1024;
    float* cd1 = ws + off; off += (size_t)B_ * 1024;
    float* zx  = ws + off;

    size_t availf = (ws_size / 4 > off) ? (ws_size / 4 - off) : 0;
    int TC = 0;                           // even tiers (xconv0 pairs timesteps)
    if      (availf >= (size_t)100 * B_ * 8192) TC = 100;
    else if (availf >= (size_t)50  * B_ * 8192) TC = 50;
    else if (availf >= (size_t)20  * B_ * 8192) TC = 20;
    else if (availf >= (size_t)10  * B_ * 8192) TC = 10;

    enc_kernel<<<B_, 256, 0, stream>>>(x, ew0, eb0, ew1, eb1, seq, h1f, c1f, h2f, c2f);

    if (TC > 0) {
        for (int t0 = 0; t0 < T_; t0 += TC) {
            xconv0_kernel<<<(TC / 2) * B_, 256, 0, stream>>>(seq, dw0, zx, t0);
            dec0k<<<B_, 256, 0, stream>>>(
                dw0, db0, seq, zx,
                t0 == 0 ? h2f : hd0, t0 == 0 ? c2f : cd0, hd0, cd0, t0, TC);
        }
        for (int t0 = 0; t0 < T_; t0 += TC) {
            xconv1_kernel<<<TC * B_, 256, 0, stream>>>(seq, dw1, zx, t0);
            dec1k<<<B_, 512, 0, stream>>>(
                dw1, db1, zx,
                t0 == 0 ? h1f : hd1, t0 == 0 ? c1f : cd1, hd1, cd1,
                fw, fb, out, t0, TC);
        }
    } else {
        dec0_fb<<<B_, 512, 0, stream>>>(dw0, db0, seq, h2f, c2f);
        dec1_fb<<<B_, 512, 0, stream>>>(dw1, db1, seq, h1f, c1f, fw, fb, out);
    }
}

// Round 9
// 2623.712 us; speedup vs baseline: 1.1098x; 1.1098x over previous
//
#include <hip/hip_runtime.h>
#include <math.h>

#define B_ 128
#define T_ 100
#define RS 72      // padded row stride (words); data cols [4..67]; [0..3],[68..71] zero
#define ZS1 68     // partial/reduction buffer stride (68 mod 32 = 4 -> bank spread)

// ---------------------------------------------------------------------------
// Fast transcendentals (~1e-6 rel err; threshold 1.27e-4)
// ---------------------------------------------------------------------------
__device__ __forceinline__ float frcp_(float x){ return __builtin_amdgcn_rcpf(x); }
__device__ __forceinline__ float fsig_(float x){ return frcp_(1.f + __expf(-x)); }
__device__ __forceinline__ float ftanh_(float x){ float e = __expf(2.f*x); return 1.f - 2.f*frcp_(e+1.f); }
__device__ __forceinline__ float gate1(float zi, float zf, float zo, float zg, float& c){
    float cc = fsig_(zf)*c + fsig_(zi)*ftanh_(zg);
    c = cc;
    return fsig_(zo)*ftanh_(cc);
}
__device__ __forceinline__ float4 ldf4(const float* p){ return *reinterpret_cast<const float4*>(p); }
__device__ __forceinline__ void stf4(float* p, float4 v){ *reinterpret_cast<float4*>(p) = v; }
__device__ __forceinline__ float2 ldf2(const float* p){ return *reinterpret_cast<const float2*>(p); }
__device__ __forceinline__ void stf2(float* p, float2 v){ *reinterpret_cast<float2*>(p) = v; }
__device__ __forceinline__ float4 add4(float4 a, float4 b){
    return make_float4(a.x+b.x, a.y+b.y, a.z+b.z, a.w+b.w);
}
__device__ __forceinline__ float4 gate4(float4 zi, float4 zf, float4 zo, float4 zg,
                                        float bi, float bf, float bo, float bg, float4& c){
    float4 h;
    h.x = gate1(zi.x+bi, zf.x+bf, zo.x+bo, zg.x+bg, c.x);
    h.y = gate1(zi.y+bi, zf.y+bf, zo.y+bo, zg.y+bg, c.y);
    h.z = gate1(zi.z+bi, zf.z+bf, zo.z+bo, zg.z+bg, c.z);
    h.w = gate1(zi.w+bi, zf.w+bf, zo.w+bo, zg.w+bg, c.w);
    return h;
}

__device__ __forceinline__ void fma4v(float w, float u0,float u1,float u2,float u3, float4& a){
    a.x = fmaf(w,u0,a.x); a.y = fmaf(w,u1,a.y);
    a.z = fmaf(w,u2,a.z); a.w = fmaf(w,u3,a.w);
}
__device__ __forceinline__ void fma2v(float w, float u0,float u1, float2& a){
    a.x = fmaf(w,u0,a.x); a.y = fmaf(w,u1,a.y);
}

// ---------------------------------------------------------------------------
// Row accumulators, weights from LDS. rowp = &buf[row*RS + 4 + f0].
// wk = wl + (krow*3)*ROWS + ch*4 ; tap d weight float4 at wk + d*ROWS.
// ---------------------------------------------------------------------------
template<int ROWS>
__device__ __forceinline__ void rowacc4(const float* __restrict__ rowp,
                                        const float* __restrict__ wk,
                                        float4& ai, float4& af, float4& ao, float4& ag)
{
    float  m = rowp[-1];
    float4 a = ldf4(rowp);
    float  p = rowp[4];
    float4 wa = ldf4(wk);
    float4 wb = ldf4(wk + ROWS);
    float4 wc = ldf4(wk + 2*ROWS);
    fma4v(wa.x, m,a.x,a.y,a.z, ai);  fma4v(wa.y, m,a.x,a.y,a.z, af);
    fma4v(wa.z, m,a.x,a.y,a.z, ao);  fma4v(wa.w, m,a.x,a.y,a.z, ag);
    fma4v(wb.x, a.x,a.y,a.z,a.w, ai); fma4v(wb.y, a.x,a.y,a.z,a.w, af);
    fma4v(wb.z, a.x,a.y,a.z,a.w, ao); fma4v(wb.w, a.x,a.y,a.z,a.w, ag);
    fma4v(wc.x, a.y,a.z,a.w,p, ai);  fma4v(wc.y, a.y,a.z,a.w,p, af);
    fma4v(wc.z, a.y,a.z,a.w,p, ao);  fma4v(wc.w, a.y,a.z,a.w,p, ag);
}
template<int ROWS>
__device__ __forceinline__ void rowacc2(const float* __restrict__ rowp,
                                        const float* __restrict__ wk,
                                        float2& ai, float2& af, float2& ao, float2& ag)
{
    float  m = rowp[-1];
    float2 a = ldf2(rowp);
    float  p = rowp[2];
    float4 wa = ldf4(wk);
    float4 wb = ldf4(wk + ROWS);
    float4 wc = ldf4(wk + 2*ROWS);
    fma2v(wa.x, m,a.x, ai); fma2v(wa.y, m,a.x, af);
    fma2v(wa.z, m,a.x, ao); fma2v(wa.w, m,a.x, ag);
    fma2v(wb.x, a.x,a.y, ai); fma2v(wb.y, a.x,a.y, af);
    fma2v(wb.z, a.x,a.y, ao); fma2v(wb.w, a.x,a.y, ag);
    fma2v(wc.x, a.y,p, ai); fma2v(wc.y, a.y,p, af);
    fma2v(wc.z, a.y,p, ao); fma2v(wc.w, a.y,p, ag);
}
template<int ROWS>
__device__ __forceinline__ void rowacc8(const float* __restrict__ rowp,
                                        const float* __restrict__ wk,
                                        float4& i0, float4& i1, float4& f0v, float4& f1v,
                                        float4& o0, float4& o1, float4& g0, float4& g1)
{
    float  m = rowp[-1];
    float4 a = ldf4(rowp);
    float4 b = ldf4(rowp + 4);
    float  p = rowp[8];
    float4 wa = ldf4(wk);
    float4 wb = ldf4(wk + ROWS);
    float4 wc = ldf4(wk + 2*ROWS);
    fma4v(wa.x, m,a.x,a.y,a.z, i0);   fma4v(wa.x, a.w,b.x,b.y,b.z, i1);
    fma4v(wa.y, m,a.x,a.y,a.z, f0v);  fma4v(wa.y, a.w,b.x,b.y,b.z, f1v);
    fma4v(wa.z, m,a.x,a.y,a.z, o0);   fma4v(wa.z, a.w,b.x,b.y,b.z, o1);
    fma4v(wa.w, m,a.x,a.y,a.z, g0);   fma4v(wa.w, a.w,b.x,b.y,b.z, g1);
    fma4v(wb.x, a.x,a.y,a.z,a.w, i0); fma4v(wb.x, b.x,b.y,b.z,b.w, i1);
    fma4v(wb.y, a.x,a.y,a.z,a.w, f0v);fma4v(wb.y, b.x,b.y,b.z,b.w, f1v);
    fma4v(wb.z, a.x,a.y,a.z,a.w, o0); fma4v(wb.z, b.x,b.y,b.z,b.w, o1);
    fma4v(wb.w, a.x,a.y,a.z,a.w, g0); fma4v(wb.w, b.x,b.y,b.z,b.w, g1);
    fma4v(wc.x, a.y,a.z,a.w,b.x, i0); fma4v(wc.x, b.y,b.z,b.w,p, i1);
    fma4v(wc.y, a.y,a.z,a.w,b.x, f0v);fma4v(wc.y, b.y,b.z,b.w,p, f1v);
    fma4v(wc.z, a.y,a.z,a.w,b.x, o0); fma4v(wc.z, b.y,b.z,b.w,p, o1);
    fma4v(wc.w, a.y,a.z,a.w,b.x, g0); fma4v(wc.w, b.y,b.z,b.w,p, g1);
}

// ---------------------------------------------------------------------------
// Encoder. 1024 threads (16 waves = 4/SIMD for latency hiding), kg=2.
// L1: FT=4 (32ch x 16 f-quads), L0: FT=2. Cell states in kg0 registers.
// hbuf rows: 0,1 = x double-buffer; 2..17 = h0; 18..49 = h1.
// 2 barriers/step. P1: acc L1(t) + L0(t+1), kg1 -> zs. P2: kg0 combines.
// ---------------------------------------------------------------------------
__global__ __launch_bounds__(1024) void enc_kernel(
    const float* __restrict__ x,
    const float* __restrict__ w0, const float* __restrict__ b0,
    const float* __restrict__ w1, const float* __restrict__ b1,
    float* __restrict__ seq,
    float* __restrict__ h1f, float* __restrict__ c1f,
    float* __restrict__ h2f, float* __restrict__ c2f)
{
    __shared__ float wl0[51 * 64];        // (ci*3+d)*64 + ch*4+g, ci<17
    __shared__ float wl1[144 * 128];      // (ci*3+d)*128 + ch*4+g, ci<48
    __shared__ float hbuf[50 * RS];
    __shared__ float zsA[4 * 16 * ZS1];   // L0 partials (kg1)
    __shared__ float zsB[4 * 32 * ZS1];   // L1 partials (kg1)

    const int tid = threadIdx.x;
    const int b = blockIdx.x;
    const int kg = tid >> 9;              // 0/1 (waves 0-7 / 8-15)
    const int r  = tid & 511;
    const int chB = r >> 4, fqB = (r & 15) * 4;   // L1 lane
    const int chA = r >> 5, f0A = (r & 31) * 2;   // L0 lane

    for (int idx = tid; idx < 51 * 64; idx += 1024) {
        int k = idx >> 6, rr = idx & 63;
        int ch = rr >> 2, g = rr & 3;
        int ci = k / 3, d = k - ci * 3;
        wl0[idx] = w0[((g * 16 + ch) * 17 + ci) * 9 + d * 3 + 1];
    }
    for (int idx = tid; idx < 144 * 128; idx += 1024) {
        int k = idx >> 7, rr = idx & 127;
        int ch = rr >> 2, g = rr & 3;
        int ci = k / 3, d = k - ci * 3;
        wl1[idx] = w1[((g * 32 + ch) * 48 + ci) * 9 + d * 3 + 1];
    }
    for (int i = tid; i < 50 * RS; i += 1024) hbuf[i] = 0.f;
    for (int i = tid; i < 4 * 16 * ZS1; i += 1024) zsA[i] = 0.f;   // prologue reads zero

    const float biA = b0[chA], bfA = b0[16 + chA], boA = b0[32 + chA], bgA = b0[48 + chA];
    const float biB = b1[chB], bfB = b1[32 + chB], boB = b1[64 + chB], bgB = b1[96 + chB];
    __syncthreads();

    if (tid < 64) hbuf[0 * RS + 4 + tid] = x[(size_t)b * T_ * 64 + tid];   // x(0)
    __syncthreads();

    const float4 z4 = make_float4(0.f, 0.f, 0.f, 0.f);
    const float2 z2 = make_float2(0.f, 0.f);
    float2 c0 = z2;                       // L0 cell (kg0)
    float4 c1 = z4;                       // L1 cell (kg0)

    // ---- prologue: h0(0) from x(0) (h0/h1 zero; zsA zeroed) ----
    {
        float2 ai2 = z2, af2 = z2, ao2 = z2, ag2 = z2;
        if (kg == 0) {
            rowacc2<64>(&hbuf[0 * RS + 4 + f0A], &wl0[chA * 4], ai2, af2, ao2, ag2);
        } else if (r < 64 && T_ > 1) {
            hbuf[1 * RS + 4 + r] = x[((size_t)b * T_ + 1) * 64 + r];      // x(1)
        }
        __syncthreads();
        if (kg == 0) {
            float2 pa = ldf2(&zsA[(0*16+chA)*ZS1 + f0A]);
            float2 pf = ldf2(&zsA[(1*16+chA)*ZS1 + f0A]);
            float2 po = ldf2(&zsA[(2*16+chA)*ZS1 + f0A]);
            float2 pg = ldf2(&zsA[(3*16+chA)*ZS1 + f0A]);
            float2 h0;
            h0.x = gate1(ai2.x+pa.x+biA, af2.x+pf.x+bfA, ao2.x+po.x+boA, ag2.x+pg.x+bgA, c0.x);
            h0.y = gate1(ai2.y+pa.y+biA, af2.y+pf.y+bfA, ao2.y+po.y+boA, ag2.y+pg.y+bgA, c0.y);
            stf2(&hbuf[(2 + chA) * RS + 4 + f0A], h0);
        }
        __syncthreads();
    }

#pragma unroll 1
    for (int t = 0; t < T_; ++t) {
        const bool doL0 = (t + 1 < T_);
        // ---------------- P1: accumulate ----------------
        float4 ai4 = z4, af4 = z4, ao4 = z4, ag4 = z4;    // L1(t), FT=4
        float2 ai2 = z2, af2 = z2, ao2 = z2, ag2 = z2;    // L0(t+1), FT=2
        if (kg == 0) {
#pragma unroll 1
            for (int ci = 0; ci < 24; ++ci)
                rowacc4<128>(&hbuf[(2 + ci) * RS + 4 + fqB],
                             &wl1[(ci * 3) * 128 + chB * 4], ai4, af4, ao4, ag4);
            if (doL0) {
                rowacc2<64>(&hbuf[((t + 1) & 1) * RS + 4 + f0A], &wl0[chA * 4],
                            ai2, af2, ao2, ag2);
#pragma unroll 1
                for (int j = 0; j < 8; ++j)
                    rowacc2<64>(&hbuf[(2 + j) * RS + 4 + f0A],
                                &wl0[((1 + j) * 3) * 64 + chA * 4], ai2, af2, ao2, ag2);
            }
        } else {
#pragma unroll 1
            for (int ci = 24; ci < 48; ++ci)
                rowacc4<128>(&hbuf[(2 + ci) * RS + 4 + fqB],
                             &wl1[(ci * 3) * 128 + chB * 4], ai4, af4, ao4, ag4);
            if (doL0) {
#pragma unroll 1
                for (int j = 8; j < 16; ++j)
                    rowacc2<64>(&hbuf[(2 + j) * RS + 4 + f0A],
                                &wl0[((1 + j) * 3) * 64 + chA * 4], ai2, af2, ao2, ag2);
                stf2(&zsA[(0*16+chA)*ZS1 + f0A], ai2);
                stf2(&zsA[(1*16+chA)*ZS1 + f0A], af2);
                stf2(&zsA[(2*16+chA)*ZS1 + f0A], ao2);
                stf2(&zsA[(3*16+chA)*ZS1 + f0A], ag2);
            }
            stf4(&zsB[(0*32+chB)*ZS1 + fqB], ai4);
            stf4(&zsB[(1*32+chB)*ZS1 + fqB], af4);
            stf4(&zsB[(2*32+chB)*ZS1 + fqB], ao4);
            stf4(&zsB[(3*32+chB)*ZS1 + fqB], ag4);
            if (r < 64 && t + 2 < T_)
                hbuf[(t & 1) * RS + 4 + r] = x[((size_t)b * T_ + t + 2) * 64 + r];
        }
        __syncthreads();                                   // Y
        // ---------------- P2: kg0 combines ----------------
        if (kg == 0) {
            float4 zi = add4(ai4, ldf4(&zsB[(0*32+chB)*ZS1 + fqB]));
            float4 zf = add4(af4, ldf4(&zsB[(1*32+chB)*ZS1 + fqB]));
            float4 zo = add4(ao4, ldf4(&zsB[(2*32+chB)*ZS1 + fqB]));
            float4 zg = add4(ag4, ldf4(&zsB[(3*32+chB)*ZS1 + fqB]));
            float4 h1q = gate4(zi, zf, zo, zg, biB, bfB, boB, bgB, c1);
            stf4(&hbuf[(18 + chB) * RS + 4 + fqB], h1q);
            stf4(&seq[((size_t)t * B_ + b) * 2048 + chB * 64 + fqB], h1q);
            if (doL0) {
                float2 pa = ldf2(&zsA[(0*16+chA)*ZS1 + f0A]);
                float2 pf = ldf2(&zsA[(1*16+chA)*ZS1 + f0A]);
                float2 po = ldf2(&zsA[(2*16+chA)*ZS1 + f0A]);
                float2 pg = ldf2(&zsA[(3*16+chA)*ZS1 + f0A]);
                float2 h0;
                h0.x = gate1(ai2.x+pa.x+biA, af2.x+pf.x+bfA,
                             ao2.x+po.x+boA, ag2.x+pg.x+bgA, c0.x);
                h0.y = gate1(ai2.y+pa.y+biA, af2.y+pf.y+bfA,
                             ao2.y+po.y+boA, ag2.y+pg.y+bgA, c0.y);
                stf2(&hbuf[(2 + chA) * RS + 4 + f0A], h0);
            }
        }
        __syncthreads();                                   // Z
    }

    // final states: h from hbuf, c from kg0 registers
    if (tid < 1024) {
        int ch = tid >> 6, f = tid & 63;
        h1f[b * 1024 + tid] = hbuf[(2 + ch) * RS + 4 + f];
    }
    for (int i = tid; i < 2048; i += 1024) {
        int ch = i >> 6, f = i & 63;
        h2f[b * 2048 + i] = hbuf[(18 + ch) * RS + 4 + f];
    }
    if (kg == 0) {
        stf2(&c1f[(b * 16 + chA) * 64 + f0A], c0);
        stf4(&c2f[b * 2048 + chB * 64 + fqB], c1);
    }
}

// ---------------------------------------------------------------------------
// xconv0: x-part pre-activations for dec0. One block per (t,b). (r7 form)
// ---------------------------------------------------------------------------
__global__ __launch_bounds__(256, 2) void xconv0_kernel(
    const float* __restrict__ seqIn, const float* __restrict__ w,
    float* __restrict__ zx, int t0)
{
    __shared__ float wl[96 * 128];
    __shared__ float xt[32 * RS];

    const int tid = threadIdx.x;
    const int tl = blockIdx.x / B_;
    const int b  = blockIdx.x - tl * B_;
    const int t  = t0 + tl;

    for (int idx = tid; idx < 96 * 128; idx += 256) {
        int k = idx >> 7, rr = idx & 127;
        int ch = rr >> 2, g = rr & 3;
        int ci = k / 3, d = k - ci * 3;
        wl[idx] = w[((g * 32 + ch) * 64 + ci) * 9 + d * 3 + 1];
    }
    {
        int rr = tid >> 3, j = tid & 7;
        xt[rr * RS + (j < 4 ? j : 64 + j)] = 0.f;
    }
    {
        const float* s = &seqIn[((size_t)t * B_ + b) * 2048 + tid * 8];
        float4 v0 = ldf4(s);
        float4 v1 = ldf4(s + 4);
        int ci = tid >> 3, col = (tid & 7) * 8;
        stf4(&xt[ci * RS + 4 + col], v0);
        stf4(&xt[ci * RS + 4 + col + 4], v1);
    }
    __syncthreads();

    const int ch = tid >> 3, f0 = (tid & 7) * 8;
    const float4 z4 = make_float4(0.f,0.f,0.f,0.f);
    float4 i0=z4,i1=z4,f0v=z4,f1v=z4,o0=z4,o1=z4,g0=z4,g1=z4;
#pragma unroll 1
    for (int rr = 0; rr < 32; ++rr)
        rowacc8<128>(&xt[rr * RS + 4 + f0], wl + (rr * 3) * 128 + ch * 4,
                     i0, i1, f0v, f1v, o0, o1, g0, g1);

    float* zp = &zx[(((size_t)tl * B_ + b) * 4) * 2048 + ch * 64 + f0];
    stf4(zp, i0);            stf4(zp + 4, i1);
    stf4(zp + 2048, f0v);    stf4(zp + 2048 + 4, f1v);
    stf4(zp + 4096, o0);     stf4(zp + 4096 + 4, o1);
    stf4(zp + 6144, g0);     stf4(zp + 6144 + 4, g1);
}

// ---------------------------------------------------------------------------
// xconv1: x-part for dec1 (32 -> 16ch). One block per (t,b). (r7 form)
// ---------------------------------------------------------------------------
__global__ __launch_bounds__(256, 2) void xconv1_kernel(
    const float* __restrict__ seqIn, const float* __restrict__ w,
    float* __restrict__ zx, int t0)
{
    __shared__ float wl[96 * 64];
    __shared__ float xt[32 * RS];

    const int tid = threadIdx.x;
    const int tl = blockIdx.x / B_;
    const int b  = blockIdx.x - tl * B_;
    const int t  = t0 + tl;

    for (int idx = tid; idx < 96 * 64; idx += 256) {
        int k = idx >> 6, rr = idx & 63;
        int ch = rr >> 2, g = rr & 3;
        int ci = k / 3, d = k - ci * 3;
        wl[idx] = w[((g * 16 + ch) * 48 + ci) * 9 + d * 3 + 1];
    }
    {
        int rr = tid >> 3, j = tid & 7;
        xt[rr * RS + (j < 4 ? j : 64 + j)] = 0.f;
    }
    {
        const float* s = &seqIn[((size_t)t * B_ + b) * 2048 + tid * 8];
        float4 v0 = ldf4(s);
        float4 v1 = ldf4(s + 4);
        int ci = tid >> 3, col = (tid & 7) * 8;
        stf4(&xt[ci * RS + 4 + col], v0);
        stf4(&xt[ci * RS + 4 + col + 4], v1);
    }
    __syncthreads();

    const int ch = tid >> 4, f0 = (tid & 15) * 4;
    const float4 z4 = make_float4(0.f,0.f,0.f,0.f);
    float4 ai=z4, af=z4, ao=z4, ag=z4;
#pragma unroll 1
    for (int rr = 0; rr < 32; ++rr)
        rowacc4<64>(&xt[rr * RS + 4 + f0], wl + (rr * 3) * 64 + ch * 4, ai, af, ao, ag);

    float* zp = &zx[(((size_t)tl * B_ + b) * 4) * 1024 + ch * 64 + f0];
    stf4(zp, ai);
    stf4(zp + 1024, af);
    stf4(zp + 2048, ao);
    stf4(zp + 3072, ag);
}

// ---------------------------------------------------------------------------
// dec0k: decoder L0 h-recurrence. 1024 thr (4 waves/SIMD), kg=2, FT=4.
// zx prefetched into kg0 regs during P1. 2 barriers/step.
// ---------------------------------------------------------------------------
__global__ __launch_bounds__(1024) void dec0k(
    const float* __restrict__ w, const float* __restrict__ bias,
    float* __restrict__ seq, const float* __restrict__ zx,
    const float* __restrict__ hin, const float* __restrict__ cin,
    float* __restrict__ hout, float* __restrict__ cout,
    int t0, int tn)
{
    __shared__ float wl[96 * 128];        // h rows (w rows 32..63)
    __shared__ float hp[32 * RS];
    __shared__ float zs[4 * 32 * ZS1];

    const int tid = threadIdx.x, b = blockIdx.x;
    const int kg = tid >> 9;
    const int r  = tid & 511;
    const int ch = r >> 4, fq = (r & 15) * 4;

    for (int idx = tid; idx < 96 * 128; idx += 1024) {
        int k = idx >> 7, rr = idx & 127;
        int c8 = rr >> 2, g = rr & 3;
        int ci = k / 3, d = k - ci * 3;
        wl[idx] = w[((g * 32 + c8) * 64 + 32 + ci) * 9 + d * 3 + 1];
    }
    for (int i = tid; i < 32 * RS; i += 1024) hp[i] = 0.f;
    const float bi = bias[ch], bf = bias[32 + ch], bo = bias[64 + ch], bg = bias[96 + ch];
    __syncthreads();
    for (int i = tid; i < 2048; i += 1024) {
        int c8 = i >> 6, f = i & 63;
        hp[c8 * RS + 4 + f] = hin[b * 2048 + i];
    }
    const float4 z4 = make_float4(0.f, 0.f, 0.f, 0.f);
    float4 ca = z4;
    if (kg == 0) ca = ldf4(&cin[b * 2048 + ch * 64 + fq]);
    __syncthreads();

#pragma unroll 1
    for (int tl = 0; tl < tn; ++tl) {
        const int t = t0 + tl;
        float4 xi = z4, xf = z4, xo = z4, xg = z4;
        if (kg == 0) {      // prefetch x-part (latency hidden by the row loop)
            const float* zp0 = &zx[((size_t)tl * B_ + b) * 8192 + ch * 64 + fq];
            xi = ldf4(zp0);
            xf = ldf4(zp0 + 2048);
            xo = ldf4(zp0 + 4096);
            xg = ldf4(zp0 + 6144);
        }
        float4 ai = z4, af = z4, ao = z4, ag = z4;
#pragma unroll 1
        for (int j = 0; j < 16; ++j) {
            const int ci = kg * 16 + j;
            rowacc4<128>(&hp[ci * RS + 4 + fq], &wl[(ci * 3) * 128 + ch * 4],
                         ai, af, ao, ag);
        }
        if (kg == 1) {
            stf4(&zs[(0*32+ch)*ZS1 + fq], ai);
            stf4(&zs[(1*32+ch)*ZS1 + fq], af);
            stf4(&zs[(2*32+ch)*ZS1 + fq], ao);
            stf4(&zs[(3*32+ch)*ZS1 + fq], ag);
        }
        __syncthreads();                                   // Y
        if (kg == 0) {
            float4 zi = add4(add4(ai, xi), ldf4(&zs[(0*32+ch)*ZS1 + fq]));
            float4 zf = add4(add4(af, xf), ldf4(&zs[(1*32+ch)*ZS1 + fq]));
            float4 zo = add4(add4(ao, xo), ldf4(&zs[(2*32+ch)*ZS1 + fq]));
            float4 zg = add4(add4(ag, xg), ldf4(&zs[(3*32+ch)*ZS1 + fq]));
            float4 hq = gate4(zi, zf, zo, zg, bi, bf, bo, bg, ca);
            stf4(&hp[ch * RS + 4 + fq], hq);
            stf4(&seq[((size_t)t * B_ + b) * 2048 + ch * 64 + fq], hq);
        }
        __syncthreads();                                   // Z
    }

    for (int i = tid; i < 2048; i += 1024) {
        int c8 = i >> 6, f = i & 63;
        hout[b * 2048 + i] = hp[c8 * RS + 4 + f];
    }
    if (kg == 0) stf4(&cout[b * 2048 + ch * 64 + fq], ca);
}

// ---------------------------------------------------------------------------
// dec1k: decoder L1 h-recurrence + final 1x1 conv. 1024 thr, kg=2, FT=2.
// fc(t-1) computed during P1(t); tail after loop.
// ---------------------------------------------------------------------------
__global__ __launch_bounds__(1024) void dec1k(
    const float* __restrict__ w, const float* __restrict__ bias,
    const float* __restrict__ zx,
    const float* __restrict__ hin, const float* __restrict__ cin,
    float* __restrict__ hout, float* __restrict__ cout,
    const float* __restrict__ fw, const float* __restrict__ fb,
    float* __restrict__ out, int t0, int tn)
{
    __shared__ float wl[48 * 64];         // h rows (w rows 32..47)
    __shared__ float hp[16 * RS];
    __shared__ float zs[4 * 16 * ZS1];
    __shared__ float fcw[16];
    __shared__ float fcb;

    const int tid = threadIdx.x, b = blockIdx.x;
    const int kg = tid >> 9;
    const int r  = tid & 511;
    const int ch = r >> 5, f0 = (r & 31) * 2;

    for (int idx = tid; idx < 48 * 64; idx += 1024) {
        int k = idx >> 6, rr = idx & 63;
        int c8 = rr >> 2, g = rr & 3;
        int ci = k / 3, d = k - ci * 3;
        wl[idx] = w[((g * 16 + c8) * 48 + 32 + ci) * 9 + d * 3 + 1];
    }
    if (tid < 16) fcw[tid] = fw[tid];
    if (tid == 16) fcb = fb[0];
    for (int i = tid; i < 16 * RS; i += 1024) hp[i] = 0.f;
    const float bi = bias[ch], bf = bias[16 + ch], bo = bias[32 + ch], bg = bias[48 + ch];
    __syncthreads();
    if (tid < 1024) {
        int c8 = tid >> 6, f = tid & 63;
        hp[c8 * RS + 4 + f] = hin[b * 1024 + tid];
    }
    const float2 z2 = make_float2(0.f, 0.f);
    float2 cc = z2;
    if (kg == 0) cc = ldf2(&cin[b * 1024 + ch * 64 + f0]);
    const float fcbv = fcb;
    __syncthreads();

#pragma unroll 1
    for (int tl = 0; tl < tn; ++tl) {
        const int t = t0 + tl;
        if (tid < 64 && t > 0) {          // fc for previous step (hp = h(t-1))
            float a = fcbv;
#pragma unroll
            for (int k2 = 0; k2 < 16; ++k2)
                a = fmaf(fcw[k2], hp[k2 * RS + 4 + tid], a);
            out[(b * T_ + (t - 1)) * 64 + tid] = a;
        }
        float2 xi = z2, xf = z2, xo = z2, xg = z2;
        if (kg == 0) {
            const float* zp0 = &zx[((size_t)tl * B_ + b) * 4096 + ch * 64 + f0];
            xi = ldf2(zp0);
            xf = ldf2(zp0 + 1024);
            xo = ldf2(zp0 + 2048);
            xg = ldf2(zp0 + 3072);
        }
        float2 ai = z2, af = z2, ao = z2, ag = z2;
#pragma unroll 1
        for (int j = 0; j < 8; ++j) {
            const int ci = kg * 8 + j;
            rowacc2<64>(&hp[ci * RS + 4 + f0], &wl[(ci * 3) * 64 + ch * 4],
                        ai, af, ao, ag);
        }
        if (kg == 1) {
            stf2(&zs[(0*16+ch)*ZS1 + f0], ai);
            stf2(&zs[(1*16+ch)*ZS1 + f0], af);
            stf2(&zs[(2*16+ch)*ZS1 + f0], ao);
            stf2(&zs[(3*16+ch)*ZS1 + f0], ag);
        }
        __syncthreads();                                   // Y
        if (kg == 0) {
            float2 pa = ldf2(&zs[(0*16+ch)*ZS1 + f0]);
            float2 pf = ldf2(&zs[(1*16+ch)*ZS1 + f0]);
            float2 po = ldf2(&zs[(2*16+ch)*ZS1 + f0]);
            float2 pg = ldf2(&zs[(3*16+ch)*ZS1 + f0]);
            float2 hh;
            hh.x = gate1(ai.x+xi.x+pa.x+bi, af.x+xf.x+pf.x+bf,
                         ao.x+xo.x+po.x+bo, ag.x+xg.x+pg.x+bg, cc.x);
            hh.y = gate1(ai.y+xi.y+pa.y+bi, af.y+xf.y+pf.y+bf,
                         ao.y+xo.y+po.y+bo, ag.y+xg.y+pg.y+bg, cc.y);
            stf2(&hp[ch * RS + 4 + f0], hh);
        }
        __syncthreads();                                   // Z
    }

    if (tid < 64) {
        float a = fcbv;
#pragma unroll
        for (int k2 = 0; k2 < 16; ++k2)
            a = fmaf(fcw[k2], hp[k2 * RS + 4 + tid], a);
        out[(b * T_ + (t0 + tn - 1)) * 64 + tid] = a;
    }
    if (tid < 1024) {
        int c8 = tid >> 6, f = tid & 63;
        hout[b * 1024 + tid] = hp[c8 * RS + 4 + f];
    }
    if (kg == 0) stf2(&cout[b * 1024 + ch * 64 + f0], cc);
}

// ---------------------------------------------------------------------------
// Fallbacks (ws too small for zx): fused x+h decoders (r7, unchanged).
// ---------------------------------------------------------------------------
__global__ __launch_bounds__(512, 1) void dec0_fb(
    const float* __restrict__ w, const float* __restrict__ bias,
    float* __restrict__ seq,
    const float* __restrict__ hin, const float* __restrict__ cin)
{
    __shared__ float wl[192 * 128];
    __shared__ float bs[128];
    __shared__ float xin[32 * RS];
    __shared__ float hp[32 * RS];

    const int tid = threadIdx.x;
    const int b = blockIdx.x;

    for (int idx = tid; idx < 192 * 128; idx += 512) {
        int k = idx >> 7, rr = idx & 127;
        int ch = rr >> 2, g = rr & 3;
        int ci = k / 3, d = k - ci * 3;
        wl[idx] = w[((g * 32 + ch) * 64 + ci) * 9 + d * 3 + 1];
    }
    if (tid < 128) bs[tid] = bias[tid];
    for (int i = tid; i < 32 * RS; i += 512) { xin[i] = 0.f; hp[i] = 0.f; }
    __syncthreads();
    {
        const float* hs = &hin[b * 2048 + tid * 4];
        float4 hv = ldf4(hs);
        int ci = tid >> 4, col = (tid & 15) * 4;
        stf4(&hp[ci * RS + 4 + col], hv);
    }
    const int ch = tid >> 4, f0 = (tid & 15) * 4;
    float4 cc = ldf4(&cin[b * 2048 + ch * 64 + f0]);
    const float bi = bs[ch], bf = bs[32 + ch], bo = bs[64 + ch], bg = bs[96 + ch];
    const float4 z4 = make_float4(0.f,0.f,0.f,0.f);

    float4 nx = ldf4(&seq[(size_t)b * 2048 + tid * 4]);

#pragma unroll 1
    for (int t = 0; t < T_; ++t) {
        {
            int ci = tid >> 4, col = (tid & 15) * 4;
            stf4(&xin[ci * RS + 4 + col], nx);
        }
        __syncthreads();
        if (t + 1 < T_)
            nx = ldf4(&seq[((size_t)(t + 1) * B_ + b) * 2048 + tid * 4]);
        float4 ai = z4, af = z4, ao = z4, ag = z4;
#pragma unroll 1
        for (int rr = 0; rr < 32; ++rr)
            rowacc4<128>(&xin[rr * RS + 4 + f0], wl + (rr * 3) * 128 + ch * 4, ai, af, ao, ag);
#pragma unroll 1
        for (int rr = 0; rr < 32; ++rr)
            rowacc4<128>(&hp[rr * RS + 4 + f0], wl + ((32 + rr) * 3) * 128 + ch * 4, ai, af, ao, ag);
        float4 hn = gate4(ai, af, ao, ag, bi, bf, bo, bg, cc);
        __syncthreads();
        stf4(&hp[ch * RS + 4 + f0], hn);
        stf4(&seq[((size_t)t * B_ + b) * 2048 + ch * 64 + f0], hn);
    }
}

__global__ __launch_bounds__(512, 1) void dec1_fb(
    const float* __restrict__ w, const float* __restrict__ bias,
    const float* __restrict__ seq,
    const float* __restrict__ hin, const float* __restrict__ cin,
    const float* __restrict__ fw, const float* __restrict__ fb,
    float* __restrict__ out)
{
    __shared__ float wl[144 * 64];
    __shared__ float bs[64];
    __shared__ float xin[32 * RS];
    __shared__ float hp[16 * RS];
    __shared__ float fcw[16];
    __shared__ float fcb;

    const int tid = threadIdx.x;
    const int b = blockIdx.x;

    for (int idx = tid; idx < 144 * 64; idx += 512) {
        int k = idx >> 6, rr = idx & 63;
        int ch = rr >> 2, g = rr & 3;
        int ci = k / 3, d = k - ci * 3;
        wl[idx] = w[((g * 16 + ch) * 48 + ci) * 9 + d * 3 + 1];
    }
    if (tid < 64) bs[tid] = bias[tid];
    if (tid < 16) fcw[tid] = fw[tid];
    if (tid == 16) fcb = fb[0];
    for (int i = tid; i < 32 * RS; i += 512) xin[i] = 0.f;
    for (int i = tid; i < 16 * RS; i += 512) hp[i] = 0.f;
    __syncthreads();
    {
        const float* hs = &hin[b * 1024 + tid * 2];
        float2 hv = ldf2(hs);
        int ci = tid >> 5, col = (tid & 31) * 2;
        stf2(&hp[ci * RS + 4 + col], hv);
    }
    const int ch = tid >> 5, f0 = (tid & 31) * 2;
    float2 cc = ldf2(&cin[b * 1024 + ch * 64 + f0]);
    const float bi = bs[ch], bf = bs[16 + ch], bo = bs[32 + ch], bg = bs[48 + ch];
    const float2 z2 = make_float2(0.f,0.f);
    float4 nx = ldf4(&seq[(size_t)b * 2048 + tid * 4]);
    __syncthreads();

#pragma unroll 1
    for (int t = 0; t < T_; ++t) {
        {
            int ci = tid >> 4, col = (tid & 15) * 4;
            stf4(&xin[ci * RS + 4 + col], nx);
        }
        __syncthreads();
        if (t + 1 < T_)
            nx = ldf4(&seq[((size_t)(t + 1) * B_ + b) * 2048 + tid * 4]);

        float2 ai = z2, af = z2, ao = z2, ag = z2;
#pragma unroll 1
        for (int rr = 0; rr < 32; ++rr)
            rowacc2<64>(&xin[rr * RS + 4 + f0], wl + (rr * 3) * 64 + ch * 4, ai, af, ao, ag);
#pragma unroll 1
        for (int rr = 0; rr < 16; ++rr)
            rowacc2<64>(&hp[rr * RS + 4 + f0], wl + ((32 + rr) * 3) * 64 + ch * 4, ai, af, ao, ag);

        float2 hh;
        hh.x = gate1(ai.x + bi, af.x + bf, ao.x + bo, ag.x + bg, cc.x);
        hh.y = gate1(ai.y + bi, af.y + bf, ao.y + bo, ag.y + bg, cc.y);
        __syncthreads();
        stf2(&hp[ch * RS + 4 + f0], hh);
        __syncthreads();

        if (tid < 64) {
            float a = fcb;
#pragma unroll
            for (int k2 = 0; k2 < 16; ++k2)
                a = fmaf(fcw[k2], hp[k2 * RS + 4 + tid], a);
            out[(b * T_ + t) * 64 + tid] = a;
        }
    }
}

// ---------------------------------------------------------------------------
extern "C" void kernel_launch(void* const* d_in, const int* in_sizes, int n_in,
                              void* d_out, int out_size, void* d_ws, size_t ws_size,
                              hipStream_t stream)
{
    (void)in_sizes; (void)n_in; (void)out_size;
    const float* x   = (const float*)d_in[0];
    const float* ew0 = (const float*)d_in[1];
    const float* eb0 = (const float*)d_in[2];
    const float* ew1 = (const float*)d_in[3];
    const float* eb1 = (const float*)d_in[4];
    const float* dw0 = (const float*)d_in[5];
    const float* db0 = (const float*)d_in[6];
    const float* dw1 = (const float*)d_in[7];
    const float* db1 = (const float*)d_in[8];
    const float* fw  = (const float*)d_in[9];
    const float* fb  = (const float*)d_in[10];
    float* out = (float*)d_out;

    float* ws  = (float*)d_ws;
    size_t off = 0;
    float* seq = ws + off; off += (size_t)T_ * B_ * 2048;
    float* h1f = ws + off; off += (size_t)B_ * 1024;
    float* c1f = ws + off; off += (size_t)B_ * 1024;
    float* h2f = ws + off; off += (size_t)B_ * 2048;
    float* c2f = ws + off; off += (size_t)B_ * 2048;
    float* hd0 = ws + off; off += (size_t)B_ * 2048;
    float* cd0 = ws + off; off += (size_t)B_ * 2048;
    float* hd1 = ws + off; off += (size_t)B_ * 1024;
    float* cd1 = ws + off; off += (size_t)B_ * 1024;
    float* zx  = ws + off;

    size_t availf = (ws_size / 4 > off) ? (ws_size / 4 - off) : 0;
    int TC = 0;
    if      (availf >= (size_t)100 * B_ * 8192) TC = 100;
    else if (availf >= (size_t)50  * B_ * 8192) TC = 50;
    else if (availf >= (size_t)25  * B_ * 8192) TC = 25;
    else if (availf >= (size_t)10  * B_ * 8192) TC = 10;

    enc_kernel<<<B_, 1024, 0, stream>>>(x, ew0, eb0, ew1, eb1, seq, h1f, c1f, h2f, c2f);

    if (TC > 0) {
        for (int t0 = 0; t0 < T_; t0 += TC) {
            xconv0_kernel<<<TC * B_, 256, 0, stream>>>(seq, dw0, zx, t0);
            dec0k<<<B_, 1024, 0, stream>>>(
                dw0, db0, seq, zx,
                t0 == 0 ? h2f : hd0, t0 == 0 ? c2f : cd0, hd0, cd0, t0, TC);
        }
        for (int t0 = 0; t0 < T_; t0 += TC) {
            xconv1_kernel<<<TC * B_, 256, 0, stream>>>(seq, dw1, zx, t0);
            dec1k<<<B_, 1024, 0, stream>>>(
                dw1, db1, zx,
                t0 == 0 ? h1f : hd1, t0 == 0 ? c1f : cd1, hd1, cd1,
                fw, fb, out, t0, TC);
        }
    } else {
        dec0_fb<<<B_, 512, 0, stream>>>(dw0, db0, seq, h2f, c2f);
        dec1_fb<<<B_, 512, 0, stream>>>(dw1, db1, seq, h1f, c1f, fw, fb, out);
    }
}

// Round 11
// 2509.285 us; speedup vs baseline: 1.1604x; 1.0456x over previous
//
#include <hip/hip_runtime.h>
#include <math.h>

#define B_ 128
#define T_ 100
#define RS 72      // padded row stride (words); data cols [4..67]; [0..3],[68..71] zero
#define ZS1 68     // partial/reduction buffer stride (68 mod 32 = 4 -> bank spread)

// ---------------------------------------------------------------------------
// Fast transcendentals (~1e-6 rel err; threshold 1.27e-4)
// ---------------------------------------------------------------------------
__device__ __forceinline__ float frcp_(float x){ return __builtin_amdgcn_rcpf(x); }
__device__ __forceinline__ float fsig_(float x){ return frcp_(1.f + __expf(-x)); }
__device__ __forceinline__ float ftanh_(float x){ float e = __expf(2.f*x); return 1.f - 2.f*frcp_(e+1.f); }
__device__ __forceinline__ float gate1(float zi, float zf, float zo, float zg, float& c){
    float cc = fsig_(zf)*c + fsig_(zi)*ftanh_(zg);
    c = cc;
    return fsig_(zo)*ftanh_(cc);
}
__device__ __forceinline__ float4 ldf4(const float* p){ return *reinterpret_cast<const float4*>(p); }
__device__ __forceinline__ void stf4(float* p, float4 v){ *reinterpret_cast<float4*>(p) = v; }
__device__ __forceinline__ float2 ldf2(const float* p){ return *reinterpret_cast<const float2*>(p); }
__device__ __forceinline__ void stf2(float* p, float2 v){ *reinterpret_cast<float2*>(p) = v; }
__device__ __forceinline__ float4 add4(float4 a, float4 b){
    return make_float4(a.x+b.x, a.y+b.y, a.z+b.z, a.w+b.w);
}
__device__ __forceinline__ float4 gate4(float4 zi, float4 zf, float4 zo, float4 zg,
                                        float bi, float bf, float bo, float bg, float4& c){
    float4 h;
    h.x = gate1(zi.x+bi, zf.x+bf, zo.x+bo, zg.x+bg, c.x);
    h.y = gate1(zi.y+bi, zf.y+bf, zo.y+bo, zg.y+bg, c.y);
    h.z = gate1(zi.z+bi, zf.z+bf, zo.z+bo, zg.z+bg, c.z);
    h.w = gate1(zi.w+bi, zf.w+bf, zo.w+bo, zg.w+bg, c.w);
    return h;
}

// ---------------------------------------------------------------------------
// Row-DPP (16-lane rows) cross-lane shifts: edge taps from neighbor lanes on
// the VALU pipe, replacing the two b32 LDS edge reads per row. Row boundary
// (bound_ctrl zero-fill) coincides with the f=0 / f=63 zero boundary.
// NOTE: wave-wide shifts (0x130/0x138) silently produce garbage on gfx950
// (r10 failed correctness through enc-L0) — only DPP16 row shifts are used.
// ---------------------------------------------------------------------------
__device__ __forceinline__ float rshr1(float v){   // lane i <- lane i-1 (16-lane row), edge -> 0
    return __int_as_float(__builtin_amdgcn_update_dpp(0, __float_as_int(v), 0x111, 0xf, 0xf, true));
}
__device__ __forceinline__ float rshl1(float v){   // lane i <- lane i+1 (16-lane row), edge -> 0
    return __int_as_float(__builtin_amdgcn_update_dpp(0, __float_as_int(v), 0x101, 0xf, 0xf, true));
}

__device__ __forceinline__ void fma4v(float w, float u0,float u1,float u2,float u3, float4& a){
    a.x = fmaf(w,u0,a.x); a.y = fmaf(w,u1,a.y);
    a.z = fmaf(w,u2,a.z); a.w = fmaf(w,u3,a.w);
}
__device__ __forceinline__ void fma2v(float w, float u0,float u1, float2& a){
    a.x = fmaf(w,u0,a.x); a.y = fmaf(w,u1,a.y);
}

// ---------------------------------------------------------------------------
// Row accumulators. rowp = &buf[row*RS + 4 + f0].
// wk = wl + (krow*3)*ROWS + ch*4 ; tap d weight float4 at wk + d*ROWS.
// rowacc4d: edge taps via row-DPP (4 LDS instrs/row instead of 6).
// Requires 16-lane f-rows (fq = (lane&15)*4, channel uniform per 16 lanes).
// ---------------------------------------------------------------------------
template<int ROWS>
__device__ __forceinline__ void rowacc4d(const float* __restrict__ rowp,
                                         const float* __restrict__ wk,
                                         float4& ai, float4& af, float4& ao, float4& ag)
{
    float4 a = ldf4(rowp);
    float  m = rshr1(a.w);
    float  p = rshl1(a.x);
    float4 wa = ldf4(wk);
    float4 wb = ldf4(wk + ROWS);
    float4 wc = ldf4(wk + 2*ROWS);
    fma4v(wa.x, m,a.x,a.y,a.z, ai);  fma4v(wa.y, m,a.x,a.y,a.z, af);
    fma4v(wa.z, m,a.x,a.y,a.z, ao);  fma4v(wa.w, m,a.x,a.y,a.z, ag);
    fma4v(wb.x, a.x,a.y,a.z,a.w, ai); fma4v(wb.y, a.x,a.y,a.z,a.w, af);
    fma4v(wb.z, a.x,a.y,a.z,a.w, ao); fma4v(wb.w, a.x,a.y,a.z,a.w, ag);
    fma4v(wc.x, a.y,a.z,a.w,p, ai);  fma4v(wc.y, a.y,a.z,a.w,p, af);
    fma4v(wc.z, a.y,a.z,a.w,p, ao);  fma4v(wc.w, a.y,a.z,a.w,p, ag);
}

// Legacy accumulators (LDS edge taps) — used for enc-L0 / xconv / fallbacks.
template<int ROWS>
__device__ __forceinline__ void rowacc4(const float* __restrict__ rowp,
                                        const float* __restrict__ wk,
                                        float4& ai, float4& af, float4& ao, float4& ag)
{
    float  m = rowp[-1];
    float4 a = ldf4(rowp);
    float  p = rowp[4];
    float4 wa = ldf4(wk);
    float4 wb = ldf4(wk + ROWS);
    float4 wc = ldf4(wk + 2*ROWS);
    fma4v(wa.x, m,a.x,a.y,a.z, ai);  fma4v(wa.y, m,a.x,a.y,a.z, af);
    fma4v(wa.z, m,a.x,a.y,a.z, ao);  fma4v(wa.w, m,a.x,a.y,a.z, ag);
    fma4v(wb.x, a.x,a.y,a.z,a.w, ai); fma4v(wb.y, a.x,a.y,a.z,a.w, af);
    fma4v(wb.z, a.x,a.y,a.z,a.w, ao); fma4v(wb.w, a.x,a.y,a.z,a.w, ag);
    fma4v(wc.x, a.y,a.z,a.w,p, ai);  fma4v(wc.y, a.y,a.z,a.w,p, af);
    fma4v(wc.z, a.y,a.z,a.w,p, ao);  fma4v(wc.w, a.y,a.z,a.w,p, ag);
}
template<int ROWS>
__device__ __forceinline__ void rowacc2(const float* __restrict__ rowp,
                                        const float* __restrict__ wk,
                                        float2& ai, float2& af, float2& ao, float2& ag)
{
    float  m = rowp[-1];
    float2 a = ldf2(rowp);
    float  p = rowp[2];
    float4 wa = ldf4(wk);
    float4 wb = ldf4(wk + ROWS);
    float4 wc = ldf4(wk + 2*ROWS);
    fma2v(wa.x, m,a.x, ai); fma2v(wa.y, m,a.x, af);
    fma2v(wa.z, m,a.x, ao); fma2v(wa.w, m,a.x, ag);
    fma2v(wb.x, a.x,a.y, ai); fma2v(wb.y, a.x,a.y, af);
    fma2v(wb.z, a.x,a.y, ao); fma2v(wb.w, a.x,a.y, ag);
    fma2v(wc.x, a.y,p, ai); fma2v(wc.y, a.y,p, af);
    fma2v(wc.z, a.y,p, ao); fma2v(wc.w, a.y,p, ag);
}
template<int ROWS>
__device__ __forceinline__ void rowacc8(const float* __restrict__ rowp,
                                        const float* __restrict__ wk,
                                        float4& i0, float4& i1, float4& f0v, float4& f1v,
                                        float4& o0, float4& o1, float4& g0, float4& g1)
{
    float  m = rowp[-1];
    float4 a = ldf4(rowp);
    float4 b = ldf4(rowp + 4);
    float  p = rowp[8];
    float4 wa = ldf4(wk);
    float4 wb = ldf4(wk + ROWS);
    float4 wc = ldf4(wk + 2*ROWS);
    fma4v(wa.x, m,a.x,a.y,a.z, i0);   fma4v(wa.x, a.w,b.x,b.y,b.z, i1);
    fma4v(wa.y, m,a.x,a.y,a.z, f0v);  fma4v(wa.y, a.w,b.x,b.y,b.z, f1v);
    fma4v(wa.z, m,a.x,a.y,a.z, o0);   fma4v(wa.z, a.w,b.x,b.y,b.z, o1);
    fma4v(wa.w, m,a.x,a.y,a.z, g0);   fma4v(wa.w, a.w,b.x,b.y,b.z, g1);
    fma4v(wb.x, a.x,a.y,a.z,a.w, i0); fma4v(wb.x, b.x,b.y,b.z,b.w, i1);
    fma4v(wb.y, a.x,a.y,a.z,a.w, f0v);fma4v(wb.y, b.x,b.y,b.z,b.w, f1v);
    fma4v(wb.z, a.x,a.y,a.z,a.w, o0); fma4v(wb.z, b.x,b.y,b.z,b.w, o1);
    fma4v(wb.w, a.x,a.y,a.z,a.w, g0); fma4v(wb.w, b.x,b.y,b.z,b.w, g1);
    fma4v(wc.x, a.y,a.z,a.w,b.x, i0); fma4v(wc.x, b.y,b.z,b.w,p, i1);
    fma4v(wc.y, a.y,a.z,a.w,b.x, f0v);fma4v(wc.y, b.y,b.z,b.w,p, f1v);
    fma4v(wc.z, a.y,a.z,a.w,b.x, o0); fma4v(wc.z, b.y,b.z,b.w,p, o1);
    fma4v(wc.w, a.y,a.z,a.w,b.x, g0); fma4v(wc.w, b.y,b.z,b.w,p, g1);
}

// ---------------------------------------------------------------------------
// Encoder. 1024 threads, kg=2, 2 barriers/step. L1: FT=4 row-DPP; L0: FT=2
// legacy (LDS edge taps — wave-DPP is broken on gfx950, r10).
// hbuf rows: 0,1 = x double-buffer; 2..17 = h0; 18..49 = h1.
// ---------------------------------------------------------------------------
__global__ __launch_bounds__(1024) void enc_kernel(
    const float* __restrict__ x,
    const float* __restrict__ w0, const float* __restrict__ b0,
    const float* __restrict__ w1, const float* __restrict__ b1,
    float* __restrict__ seq,
    float* __restrict__ h1f, float* __restrict__ c1f,
    float* __restrict__ h2f, float* __restrict__ c2f)
{
    __shared__ float wl0[51 * 64];        // (ci*3+d)*64 + ch*4+g, ci<17
    __shared__ float wl1[144 * 128];      // (ci*3+d)*128 + ch*4+g, ci<48
    __shared__ float hbuf[50 * RS];
    __shared__ float zsA[4 * 16 * ZS1];   // L0 partials (kg1)
    __shared__ float zsB[4 * 32 * ZS1];   // L1 partials (kg1)

    const int tid = threadIdx.x;
    const int b = blockIdx.x;
    const int kg = tid >> 9;              // 0/1 (waves 0-7 / 8-15)
    const int r  = tid & 511;
    const int chB = r >> 4, fqB = (r & 15) * 4;   // L1 lane (16-lane f-rows)
    const int chA = r >> 5, f0A = (r & 31) * 2;   // L0 lane (32-lane f-groups)

    for (int idx = tid; idx < 51 * 64; idx += 1024) {
        int k = idx >> 6, rr = idx & 63;
        int ch = rr >> 2, g = rr & 3;
        int ci = k / 3, d = k - ci * 3;
        wl0[idx] = w0[((g * 16 + ch) * 17 + ci) * 9 + d * 3 + 1];
    }
    for (int idx = tid; idx < 144 * 128; idx += 1024) {
        int k = idx >> 7, rr = idx & 127;
        int ch = rr >> 2, g = rr & 3;
        int ci = k / 3, d = k - ci * 3;
        wl1[idx] = w1[((g * 32 + ch) * 48 + ci) * 9 + d * 3 + 1];
    }
    for (int i = tid; i < 50 * RS; i += 1024) hbuf[i] = 0.f;
    for (int i = tid; i < 4 * 16 * ZS1; i += 1024) zsA[i] = 0.f;   // prologue reads zero

    const float biA = b0[chA], bfA = b0[16 + chA], boA = b0[32 + chA], bgA = b0[48 + chA];
    const float biB = b1[chB], bfB = b1[32 + chB], boB = b1[64 + chB], bgB = b1[96 + chB];
    __syncthreads();

    if (tid < 64) hbuf[0 * RS + 4 + tid] = x[(size_t)b * T_ * 64 + tid];   // x(0)
    __syncthreads();

    const float4 z4 = make_float4(0.f, 0.f, 0.f, 0.f);
    const float2 z2 = make_float2(0.f, 0.f);
    float2 c0 = z2;                       // L0 cell (kg0)
    float4 c1 = z4;                       // L1 cell (kg0)

    // ---- prologue: h0(0) from x(0) (h0/h1 zero; zsA zeroed) ----
    {
        float2 ai2 = z2, af2 = z2, ao2 = z2, ag2 = z2;
        if (kg == 0) {
            rowacc2<64>(&hbuf[0 * RS + 4 + f0A], &wl0[chA * 4], ai2, af2, ao2, ag2);
        } else if (r < 64 && T_ > 1) {
            hbuf[1 * RS + 4 + r] = x[((size_t)b * T_ + 1) * 64 + r];      // x(1)
        }
        __syncthreads();
        if (kg == 0) {
            float2 pa = ldf2(&zsA[(0*16+chA)*ZS1 + f0A]);
            float2 pf = ldf2(&zsA[(1*16+chA)*ZS1 + f0A]);
            float2 po = ldf2(&zsA[(2*16+chA)*ZS1 + f0A]);
            float2 pg = ldf2(&zsA[(3*16+chA)*ZS1 + f0A]);
            float2 h0;
            h0.x = gate1(ai2.x+pa.x+biA, af2.x+pf.x+bfA, ao2.x+po.x+boA, ag2.x+pg.x+bgA, c0.x);
            h0.y = gate1(ai2.y+pa.y+biA, af2.y+pf.y+bfA, ao2.y+po.y+boA, ag2.y+pg.y+bgA, c0.y);
            stf2(&hbuf[(2 + chA) * RS + 4 + f0A], h0);
        }
        __syncthreads();
    }

#pragma unroll 1
    for (int t = 0; t < T_; ++t) {
        const bool doL0 = (t + 1 < T_);
        // ---------------- P1: accumulate ----------------
        float4 ai4 = z4, af4 = z4, ao4 = z4, ag4 = z4;    // L1(t), FT=4 (DPP rows)
        float2 ai2 = z2, af2 = z2, ao2 = z2, ag2 = z2;    // L0(t+1), FT=2 (legacy)
        if (kg == 0) {
#pragma unroll 1
            for (int ci = 0; ci < 24; ++ci)
                rowacc4d<128>(&hbuf[(2 + ci) * RS + 4 + fqB],
                              &wl1[(ci * 3) * 128 + chB * 4], ai4, af4, ao4, ag4);
            if (doL0) {
                rowacc2<64>(&hbuf[((t + 1) & 1) * RS + 4 + f0A], &wl0[chA * 4],
                            ai2, af2, ao2, ag2);
#pragma unroll 1
                for (int j = 0; j < 8; ++j)
                    rowacc2<64>(&hbuf[(2 + j) * RS + 4 + f0A],
                                &wl0[((1 + j) * 3) * 64 + chA * 4], ai2, af2, ao2, ag2);
            }
        } else {
#pragma unroll 1
            for (int ci = 24; ci < 48; ++ci)
                rowacc4d<128>(&hbuf[(2 + ci) * RS + 4 + fqB],
                              &wl1[(ci * 3) * 128 + chB * 4], ai4, af4, ao4, ag4);
            if (doL0) {
#pragma unroll 1
                for (int j = 8; j < 16; ++j)
                    rowacc2<64>(&hbuf[(2 + j) * RS + 4 + f0A],
                                &wl0[((1 + j) * 3) * 64 + chA * 4], ai2, af2, ao2, ag2);
                stf2(&zsA[(0*16+chA)*ZS1 + f0A], ai2);
                stf2(&zsA[(1*16+chA)*ZS1 + f0A], af2);
                stf2(&zsA[(2*16+chA)*ZS1 + f0A], ao2);
                stf2(&zsA[(3*16+chA)*ZS1 + f0A], ag2);
            }
            stf4(&zsB[(0*32+chB)*ZS1 + fqB], ai4);
            stf4(&zsB[(1*32+chB)*ZS1 + fqB], af4);
            stf4(&zsB[(2*32+chB)*ZS1 + fqB], ao4);
            stf4(&zsB[(3*32+chB)*ZS1 + fqB], ag4);
            if (r < 64 && t + 2 < T_)
                hbuf[(t & 1) * RS + 4 + r] = x[((size_t)b * T_ + t + 2) * 64 + r];
        }
        __syncthreads();                                   // Y
        // ---------------- P2: kg0 combines ----------------
        if (kg == 0) {
            float4 zi = add4(ai4, ldf4(&zsB[(0*32+chB)*ZS1 + fqB]));
            float4 zf = add4(af4, ldf4(&zsB[(1*32+chB)*ZS1 + fqB]));
            float4 zo = add4(ao4, ldf4(&zsB[(2*32+chB)*ZS1 + fqB]));
            float4 zg = add4(ag4, ldf4(&zsB[(3*32+chB)*ZS1 + fqB]));
            float4 h1q = gate4(zi, zf, zo, zg, biB, bfB, boB, bgB, c1);
            stf4(&hbuf[(18 + chB) * RS + 4 + fqB], h1q);
            stf4(&seq[((size_t)t * B_ + b) * 2048 + chB * 64 + fqB], h1q);
            if (doL0) {
                float2 pa = ldf2(&zsA[(0*16+chA)*ZS1 + f0A]);
                float2 pf = ldf2(&zsA[(1*16+chA)*ZS1 + f0A]);
                float2 po = ldf2(&zsA[(2*16+chA)*ZS1 + f0A]);
                float2 pg = ldf2(&zsA[(3*16+chA)*ZS1 + f0A]);
                float2 h0;
                h0.x = gate1(ai2.x+pa.x+biA, af2.x+pf.x+bfA,
                             ao2.x+po.x+boA, ag2.x+pg.x+bgA, c0.x);
                h0.y = gate1(ai2.y+pa.y+biA, af2.y+pf.y+bfA,
                             ao2.y+po.y+boA, ag2.y+pg.y+bgA, c0.y);
                stf2(&hbuf[(2 + chA) * RS + 4 + f0A], h0);
            }
        }
        __syncthreads();                                   // Z
    }

    // final states
    {
        int ch = tid >> 6, f = tid & 63;
        if (tid < 1024) h1f[b * 1024 + tid] = hbuf[(2 + ch) * RS + 4 + f];
    }
    for (int i = tid; i < 2048; i += 1024) {
        int ch = i >> 6, f = i & 63;
        h2f[b * 2048 + i] = hbuf[(18 + ch) * RS + 4 + f];
    }
    if (kg == 0) {
        stf2(&c1f[(b * 16 + chA) * 64 + f0A], c0);
        stf4(&c2f[b * 2048 + chB * 64 + fqB], c1);
    }
}

// ---------------------------------------------------------------------------
// xconv0: x-part pre-activations for dec0. One block per (t,b). (unchanged)
// ---------------------------------------------------------------------------
__global__ __launch_bounds__(256, 2) void xconv0_kernel(
    const float* __restrict__ seqIn, const float* __restrict__ w,
    float* __restrict__ zx, int t0)
{
    __shared__ float wl[96 * 128];
    __shared__ float xt[32 * RS];

    const int tid = threadIdx.x;
    const int tl = blockIdx.x / B_;
    const int b  = blockIdx.x - tl * B_;
    const int t  = t0 + tl;

    for (int idx = tid; idx < 96 * 128; idx += 256) {
        int k = idx >> 7, rr = idx & 127;
        int ch = rr >> 2, g = rr & 3;
        int ci = k / 3, d = k - ci * 3;
        wl[idx] = w[((g * 32 + ch) * 64 + ci) * 9 + d * 3 + 1];
    }
    {
        int rr = tid >> 3, j = tid & 7;
        xt[rr * RS + (j < 4 ? j : 64 + j)] = 0.f;
    }
    {
        const float* s = &seqIn[((size_t)t * B_ + b) * 2048 + tid * 8];
        float4 v0 = ldf4(s);
        float4 v1 = ldf4(s + 4);
        int ci = tid >> 3, col = (tid & 7) * 8;
        stf4(&xt[ci * RS + 4 + col], v0);
        stf4(&xt[ci * RS + 4 + col + 4], v1);
    }
    __syncthreads();

    const int ch = tid >> 3, f0 = (tid & 7) * 8;
    const float4 z4 = make_float4(0.f,0.f,0.f,0.f);
    float4 i0=z4,i1=z4,f0v=z4,f1v=z4,o0=z4,o1=z4,g0=z4,g1=z4;
#pragma unroll 1
    for (int rr = 0; rr < 32; ++rr)
        rowacc8<128>(&xt[rr * RS + 4 + f0], wl + (rr * 3) * 128 + ch * 4,
                     i0, i1, f0v, f1v, o0, o1, g0, g1);

    float* zp = &zx[(((size_t)tl * B_ + b) * 4) * 2048 + ch * 64 + f0];
    stf4(zp, i0);            stf4(zp + 4, i1);
    stf4(zp + 2048, f0v);    stf4(zp + 2048 + 4, f1v);
    stf4(zp + 4096, o0);     stf4(zp + 4096 + 4, o1);
    stf4(zp + 6144, g0);     stf4(zp + 6144 + 4, g1);
}

// ---------------------------------------------------------------------------
// xconv1: x-part for dec1 (32 -> 16ch). One block per (t,b). (unchanged)
// ---------------------------------------------------------------------------
__global__ __launch_bounds__(256, 2) void xconv1_kernel(
    const float* __restrict__ seqIn, const float* __restrict__ w,
    float* __restrict__ zx, int t0)
{
    __shared__ float wl[96 * 64];
    __shared__ float xt[32 * RS];

    const int tid = threadIdx.x;
    const int tl = blockIdx.x / B_;
    const int b  = blockIdx.x - tl * B_;
    const int t  = t0 + tl;

    for (int idx = tid; idx < 96 * 64; idx += 256) {
        int k = idx >> 6, rr = idx & 63;
        int ch = rr >> 2, g = rr & 3;
        int ci = k / 3, d = k - ci * 3;
        wl[idx] = w[((g * 16 + ch) * 48 + ci) * 9 + d * 3 + 1];
    }
    {
        int rr = tid >> 3, j = tid & 7;
        xt[rr * RS + (j < 4 ? j : 64 + j)] = 0.f;
    }
    {
        const float* s = &seqIn[((size_t)t * B_ + b) * 2048 + tid * 8];
        float4 v0 = ldf4(s);
        float4 v1 = ldf4(s + 4);
        int ci = tid >> 3, col = (tid & 7) * 8;
        stf4(&xt[ci * RS + 4 + col], v0);
        stf4(&xt[ci * RS + 4 + col + 4], v1);
    }
    __syncthreads();

    const int ch = tid >> 4, f0 = (tid & 15) * 4;
    const float4 z4 = make_float4(0.f,0.f,0.f,0.f);
    float4 ai=z4, af=z4, ao=z4, ag=z4;
#pragma unroll 1
    for (int rr = 0; rr < 32; ++rr)
        rowacc4<64>(&xt[rr * RS + 4 + f0], wl + (rr * 3) * 64 + ch * 4, ai, af, ao, ag);

    float* zp = &zx[(((size_t)tl * B_ + b) * 4) * 1024 + ch * 64 + f0];
    stf4(zp, ai);
    stf4(zp + 1024, af);
    stf4(zp + 2048, ao);
    stf4(zp + 3072, ag);
}

// ---------------------------------------------------------------------------
// dec0k: decoder L0 h-recurrence. 1024 thr, kg=2, FT=4 row-DPP.
// zx prefetched into kg0 regs during P1. 2 barriers/step.
// ---------------------------------------------------------------------------
__global__ __launch_bounds__(1024) void dec0k(
    const float* __restrict__ w, const float* __restrict__ bias,
    float* __restrict__ seq, const float* __restrict__ zx,
    const float* __restrict__ hin, const float* __restrict__ cin,
    float* __restrict__ hout, float* __restrict__ cout,
    int t0, int tn)
{
    __shared__ float wl[96 * 128];        // h rows (w rows 32..63)
    __shared__ float hp[32 * RS];
    __shared__ float zs[4 * 32 * ZS1];

    const int tid = threadIdx.x, b = blockIdx.x;
    const int kg = tid >> 9;
    const int r  = tid & 511;
    const int ch = r >> 4, fq = (r & 15) * 4;

    for (int idx = tid; idx < 96 * 128; idx += 1024) {
        int k = idx >> 7, rr = idx & 127;
        int c8 = rr >> 2, g = rr & 3;
        int ci = k / 3, d = k - ci * 3;
        wl[idx] = w[((g * 32 + c8) * 64 + 32 + ci) * 9 + d * 3 + 1];
    }
    for (int i = tid; i < 32 * RS; i += 1024) hp[i] = 0.f;
    const float bi = bias[ch], bf = bias[32 + ch], bo = bias[64 + ch], bg = bias[96 + ch];
    __syncthreads();
    for (int i = tid; i < 2048; i += 1024) {
        int c8 = i >> 6, f = i & 63;
        hp[c8 * RS + 4 + f] = hin[b * 2048 + i];
    }
    const float4 z4 = make_float4(0.f, 0.f, 0.f, 0.f);
    float4 ca = z4;
    if (kg == 0) ca = ldf4(&cin[b * 2048 + ch * 64 + fq]);
    __syncthreads();

#pragma unroll 1
    for (int tl = 0; tl < tn; ++tl) {
        const int t = t0 + tl;
        float4 xi = z4, xf = z4, xo = z4, xg = z4;
        if (kg == 0) {
            const float* zp0 = &zx[((size_t)tl * B_ + b) * 8192 + ch * 64 + fq];
            xi = ldf4(zp0);
            xf = ldf4(zp0 + 2048);
            xo = ldf4(zp0 + 4096);
            xg = ldf4(zp0 + 6144);
        }
        float4 ai = z4, af = z4, ao = z4, ag = z4;
#pragma unroll 1
        for (int j = 0; j < 16; ++j) {
            const int ci = kg * 16 + j;
            rowacc4d<128>(&hp[ci * RS + 4 + fq], &wl[(ci * 3) * 128 + ch * 4],
                          ai, af, ao, ag);
        }
        if (kg == 1) {
            stf4(&zs[(0*32+ch)*ZS1 + fq], ai);
            stf4(&zs[(1*32+ch)*ZS1 + fq], af);
            stf4(&zs[(2*32+ch)*ZS1 + fq], ao);
            stf4(&zs[(3*32+ch)*ZS1 + fq], ag);
        }
        __syncthreads();                                   // Y
        if (kg == 0) {
            float4 zi = add4(add4(ai, xi), ldf4(&zs[(0*32+ch)*ZS1 + fq]));
            float4 zf = add4(add4(af, xf), ldf4(&zs[(1*32+ch)*ZS1 + fq]));
            float4 zo = add4(add4(ao, xo), ldf4(&zs[(2*32+ch)*ZS1 + fq]));
            float4 zg = add4(add4(ag, xg), ldf4(&zs[(3*32+ch)*ZS1 + fq]));
            float4 hq = gate4(zi, zf, zo, zg, bi, bf, bo, bg, ca);
            stf4(&hp[ch * RS + 4 + fq], hq);
            stf4(&seq[((size_t)t * B_ + b) * 2048 + ch * 64 + fq], hq);
        }
        __syncthreads();                                   // Z
    }

    for (int i = tid; i < 2048; i += 1024) {
        int c8 = i >> 6, f = i & 63;
        hout[b * 2048 + i] = hp[c8 * RS + 4 + f];
    }
    if (kg == 0) stf4(&cout[b * 2048 + ch * 64 + fq], ca);
}

// ---------------------------------------------------------------------------
// dec1k: decoder L1 h-recurrence + final 1x1 conv. 1024 thr, kg=4, FT=4 DPP.
// fc(t-1) computed during P1(t); tail after loop. 2 barriers/step.
// ---------------------------------------------------------------------------
__global__ __launch_bounds__(1024) void dec1k(
    const float* __restrict__ w, const float* __restrict__ bias,
    const float* __restrict__ zx,
    const float* __restrict__ hin, const float* __restrict__ cin,
    float* __restrict__ hout, float* __restrict__ cout,
    const float* __restrict__ fw, const float* __restrict__ fb,
    float* __restrict__ out, int t0, int tn)
{
    __shared__ float wl[48 * 64];         // h rows (w rows 32..47)
    __shared__ float hp[16 * RS];
    __shared__ float zs[12 * 16 * ZS1];   // 3 partial sets x 4 gates
    __shared__ float fcw[16];
    __shared__ float fcb;

    const int tid = threadIdx.x, b = blockIdx.x;
    const int kg = tid >> 8;              // 0..3
    const int r  = tid & 255;
    const int ch = r >> 4, fq = (r & 15) * 4;

    for (int idx = tid; idx < 48 * 64; idx += 1024) {
        int k = idx >> 6, rr = idx & 63;
        int c8 = rr >> 2, g = rr & 3;
        int ci = k / 3, d = k - ci * 3;
        wl[idx] = w[((g * 16 + c8) * 48 + 32 + ci) * 9 + d * 3 + 1];
    }
    if (tid < 16) fcw[tid] = fw[tid];
    if (tid == 16) fcb = fb[0];
    for (int i = tid; i < 16 * RS; i += 1024) hp[i] = 0.f;
    const float bi = bias[ch], bf = bias[16 + ch], bo = bias[32 + ch], bg = bias[48 + ch];
    __syncthreads();
    {
        int c8 = tid >> 6, f = tid & 63;
        if (tid < 1024) hp[c8 * RS + 4 + f] = hin[b * 1024 + tid];
    }
    const float4 z4 = make_float4(0.f, 0.f, 0.f, 0.f);
    float4 cc = z4;
    if (kg == 0) cc = ldf4(&cin[b * 1024 + ch * 64 + fq]);
    const float fcbv = fcb;
    __syncthreads();

#pragma unroll 1
    for (int tl = 0; tl < tn; ++tl) {
        const int t = t0 + tl;
        if (tid < 64 && t > 0) {          // fc for previous step (hp = h(t-1))
            float a = fcbv;
#pragma unroll
            for (int k2 = 0; k2 < 16; ++k2)
                a = fmaf(fcw[k2], hp[k2 * RS + 4 + tid], a);
            out[(b * T_ + (t - 1)) * 64 + tid] = a;
        }
        float4 xi = z4, xf = z4, xo = z4, xg = z4;
        if (kg == 0) {
            const float* zp0 = &zx[((size_t)tl * B_ + b) * 4096 + ch * 64 + fq];
            xi = ldf4(zp0);
            xf = ldf4(zp0 + 1024);
            xo = ldf4(zp0 + 2048);
            xg = ldf4(zp0 + 3072);
        }
        float4 ai = z4, af = z4, ao = z4, ag = z4;
#pragma unroll
        for (int j = 0; j < 4; ++j) {
            const int ci = kg * 4 + j;
            rowacc4d<64>(&hp[ci * RS + 4 + fq], &wl[(ci * 3) * 64 + ch * 4],
                         ai, af, ao, ag);
        }
        if (kg > 0) {
            float* zp = &zs[(((kg - 1) * 4 + 0) * 16 + ch) * ZS1 + fq];
            stf4(zp, ai);
            zp = &zs[(((kg - 1) * 4 + 1) * 16 + ch) * ZS1 + fq]; stf4(zp, af);
            zp = &zs[(((kg - 1) * 4 + 2) * 16 + ch) * ZS1 + fq]; stf4(zp, ao);
            zp = &zs[(((kg - 1) * 4 + 3) * 16 + ch) * ZS1 + fq]; stf4(zp, ag);
        }
        __syncthreads();                                   // Y
        if (kg == 0) {
#define ZP1(s,g) ldf4(&zs[(((s)*4+(g))*16 + ch)*ZS1 + fq])
            float4 zi = add4(add4(ai, xi), add4(ZP1(0,0), add4(ZP1(1,0), ZP1(2,0))));
            float4 zf = add4(add4(af, xf), add4(ZP1(0,1), add4(ZP1(1,1), ZP1(2,1))));
            float4 zo = add4(add4(ao, xo), add4(ZP1(0,2), add4(ZP1(1,2), ZP1(2,2))));
            float4 zg = add4(add4(ag, xg), add4(ZP1(0,3), add4(ZP1(1,3), ZP1(2,3))));
#undef ZP1
            float4 hq = gate4(zi, zf, zo, zg, bi, bf, bo, bg, cc);
            stf4(&hp[ch * RS + 4 + fq], hq);
        }
        __syncthreads();                                   // Z
    }

    if (tid < 64) {
        float a = fcbv;
#pragma unroll
        for (int k2 = 0; k2 < 16; ++k2)
            a = fmaf(fcw[k2], hp[k2 * RS + 4 + tid], a);
        out[(b * T_ + (t0 + tn - 1)) * 64 + tid] = a;
    }
    {
        int c8 = tid >> 6, f = tid & 63;
        if (tid < 1024) hout[b * 1024 + tid] = hp[c8 * RS + 4 + f];
    }
    if (kg == 0) stf4(&cout[b * 1024 + ch * 64 + fq], cc);
}

// ---------------------------------------------------------------------------
// Fallbacks (ws too small for zx): fused x+h decoders (unchanged).
// ---------------------------------------------------------------------------
__global__ __launch_bounds__(512, 1) void dec0_fb(
    const float* __restrict__ w, const float* __restrict__ bias,
    float* __restrict__ seq,
    const float* __restrict__ hin, const float* __restrict__ cin)
{
    __shared__ float wl[192 * 128];
    __shared__ float bs[128];
    __shared__ float xin[32 * RS];
    __shared__ float hp[32 * RS];

    const int tid = threadIdx.x;
    const int b = blockIdx.x;

    for (int idx = tid; idx < 192 * 128; idx += 512) {
        int k = idx >> 7, rr = idx & 127;
        int ch = rr >> 2, g = rr & 3;
        int ci = k / 3, d = k - ci * 3;
        wl[idx] = w[((g * 32 + ch) * 64 + ci) * 9 + d * 3 + 1];
    }
    if (tid < 128) bs[tid] = bias[tid];
    for (int i = tid; i < 32 * RS; i += 512) { xin[i] = 0.f; hp[i] = 0.f; }
    __syncthreads();
    {
        const float* hs = &hin[b * 2048 + tid * 4];
        float4 hv = ldf4(hs);
        int ci = tid >> 4, col = (tid & 15) * 4;
        stf4(&hp[ci * RS + 4 + col], hv);
    }
    const int ch = tid >> 4, f0 = (tid & 15) * 4;
    float4 cc = ldf4(&cin[b * 2048 + ch * 64 + f0]);
    const float bi = bs[ch], bf = bs[32 + ch], bo = bs[64 + ch], bg = bs[96 + ch];
    const float4 z4 = make_float4(0.f,0.f,0.f,0.f);

    float4 nx = ldf4(&seq[(size_t)b * 2048 + tid * 4]);

#pragma unroll 1
    for (int t = 0; t < T_; ++t) {
        {
            int ci = tid >> 4, col = (tid & 15) * 4;
            stf4(&xin[ci * RS + 4 + col], nx);
        }
        __syncthreads();
        if (t + 1 < T_)
            nx = ldf4(&seq[((size_t)(t + 1) * B_ + b) * 2048 + tid * 4]);
        float4 ai = z4, af = z4, ao = z4, ag = z4;
#pragma unroll 1
        for (int rr = 0; rr < 32; ++rr)
            rowacc4<128>(&xin[rr * RS + 4 + f0], wl + (rr * 3) * 128 + ch * 4, ai, af, ao, ag);
#pragma unroll 1
        for (int rr = 0; rr < 32; ++rr)
            rowacc4<128>(&hp[rr * RS + 4 + f0], wl + ((32 + rr) * 3) * 128 + ch * 4, ai, af, ao, ag);
        float4 hn = gate4(ai, af, ao, ag, bi, bf, bo, bg, cc);
        __syncthreads();
        stf4(&hp[ch * RS + 4 + f0], hn);
        stf4(&seq[((size_t)t * B_ + b) * 2048 + ch * 64 + f0], hn);
    }
}

__global__ __launch_bounds__(512, 1) void dec1_fb(
    const float* __restrict__ w, const float* __restrict__ bias,
    const float* __restrict__ seq,
    const float* __restrict__ hin, const float* __restrict__ cin,
    const float* __restrict__ fw, const float* __restrict__ fb,
    float* __restrict__ out)
{
    __shared__ float wl[144 * 64];
    __shared__ float bs[64];
    __shared__ float xin[32 * RS];
    __shared__ float hp[16 * RS];
    __shared__ float fcw[16];
    __shared__ float fcb;

    const int tid = threadIdx.x;
    const int b = blockIdx.x;

    for (int idx = tid; idx < 144 * 64; idx += 512) {
        int k = idx >> 6, rr = idx & 63;
        int ch = rr >> 2, g = rr & 3;
        int ci = k / 3, d = k - ci * 3;
        wl[idx] = w[((g * 16 + ch) * 48 + ci) * 9 + d * 3 + 1];
    }
    if (tid < 64) bs[tid] = bias[tid];
    if (tid < 16) fcw[tid] = fw[tid];
    if (tid == 16) fcb = fb[0];
    for (int i = tid; i < 32 * RS; i += 512) xin[i] = 0.f;
    for (int i = tid; i < 16 * RS; i += 512) hp[i] = 0.f;
    __syncthreads();
    {
        const float* hs = &hin[b * 1024 + tid * 2];
        float2 hv = ldf2(hs);
        int ci = tid >> 5, col = (tid & 31) * 2;
        stf2(&hp[ci * RS + 4 + col], hv);
    }
    const int ch = tid >> 5, f0 = (tid & 31) * 2;
    float2 cc = ldf2(&cin[b * 1024 + ch * 64 + f0]);
    const float bi = bs[ch], bf = bs[16 + ch], bo = bs[32 + ch], bg = bs[48 + ch];
    const float2 z2 = make_float2(0.f,0.f);
    float4 nx = ldf4(&seq[(size_t)b * 2048 + tid * 4]);
    __syncthreads();

#pragma unroll 1
    for (int t = 0; t < T_; ++t) {
        {
            int ci = tid >> 4, col = (tid & 15) * 4;
            stf4(&xin[ci * RS + 4 + col], nx);
        }
        __syncthreads();
        if (t + 1 < T_)
            nx = ldf4(&seq[((size_t)(t + 1) * B_ + b) * 2048 + tid * 4]);

        float2 ai = z2, af = z2, ao = z2, ag = z2;
#pragma unroll 1
        for (int rr = 0; rr < 32; ++rr)
            rowacc2<64>(&xin[rr * RS + 4 + f0], wl + (rr * 3) * 64 + ch * 4, ai, af, ao, ag);
#pragma unroll 1
        for (int rr = 0; rr < 16; ++rr)
            rowacc2<64>(&hp[rr * RS + 4 + f0], wl + ((32 + rr) * 3) * 64 + ch * 4, ai, af, ao, ag);

        float2 hh;
        hh.x = gate1(ai.x + bi, af.x + bf, ao.x + bo, ag.x + bg, cc.x);
        hh.y = gate1(ai.y + bi, af.y + bf, ao.y + bo, ag.y + bg, cc.y);
        __syncthreads();
        stf2(&hp[ch * RS + 4 + f0], hh);
        __syncthreads();

        if (tid < 64) {
            float a = fcb;
#pragma unroll
            for (int k2 = 0; k2 < 16; ++k2)
                a = fmaf(fcw[k2], hp[k2 * RS + 4 + tid], a);
            out[(b * T_ + t) * 64 + tid] = a;
        }
    }
}

// ---------------------------------------------------------------------------
extern "C" void kernel_launch(void* const* d_in, const int* in_sizes, int n_in,
                              void* d_out, int out_size, void* d_ws, size_t ws_size,
                              hipStream_t stream)
{
    (void)in_sizes; (void)n_in; (void)out_size;
    const float* x   = (const float*)d_in[0];
    const float* ew0 = (const float*)d_in[1];
    const float* eb0 = (const float*)d_in[2];
    const float* ew1 = (const float*)d_in[3];
    const float* eb1 = (const float*)d_in[4];
    const float* dw0 = (const float*)d_in[5];
    const float* db0 = (const float*)d_in[6];
    const float* dw1 = (const float*)d_in[7];
    const float* db1 = (const float*)d_in[8];
    const float* fw  = (const float*)d_in[9];
    const float* fb  = (const float*)d_in[10];
    float* out = (float*)d_out;

    float* ws  = (float*)d_ws;
    size_t off = 0;
    float* seq = ws + off; off += (size_t)T_ * B_ * 2048;
    float* h1f = ws + off; off += (size_t)B_ * 1024;
    float* c1f = ws + off; off += (size_t)B_ * 1024;
    float* h2f = ws + off; off += (size_t)B_ * 2048;
    float* c2f = ws + off; off += (size_t)B_ * 2048;
    float* hd0 = ws + off; off += (size_t)B_ * 2048;
    float* cd0 = ws + off; off += (size_t)B_ * 2048;
    float* hd1 = ws + off; off += (size_t)B_ * 1024;
    float* cd1 = ws + off; off += (size_t)B_ * 1024;
    float* zx  = ws + off;

    size_t availf = (ws_size / 4 > off) ? (ws_size / 4 - off) : 0;
    int TC = 0;
    if      (availf >= (size_t)100 * B_ * 8192) TC = 100;
    else if (availf >= (size_t)50  * B_ * 8192) TC = 50;
    else if (availf >= (size_t)25  * B_ * 8192) TC = 25;
    else if (availf >= (size_t)10  * B_ * 8192) TC = 10;

    enc_kernel<<<B_, 1024, 0, stream>>>(x, ew0, eb0, ew1, eb1, seq, h1f, c1f, h2f, c2f);

    if (TC > 0) {
        for (int t0 = 0; t0 < T_; t0 += TC) {
            xconv0_kernel<<<TC * B_, 256, 0, stream>>>(seq, dw0, zx, t0);
            dec0k<<<B_, 1024, 0, stream>>>(
                dw0, db0, seq, zx,
                t0 == 0 ? h2f : hd0, t0 == 0 ? c2f : cd0, hd0, cd0, t0, TC);
        }
        for (int t0 = 0; t0 < T_; t0 += TC) {
            xconv1_kernel<<<TC * B_, 256, 0, stream>>>(seq, dw1, zx, t0);
            dec1k<<<B_, 1024, 0, stream>>>(
                dw1, db1, zx,
                t0 == 0 ? h1f : hd1, t0 == 0 ? c1f : cd1, hd1, cd1,
                fw, fb, out, t0, TC);
        }
    } else {
        dec0_fb<<<B_, 512, 0, stream>>>(dw0, db0, seq, h2f, c2f);
        dec1_fb<<<B_, 512, 0, stream>>>(dw1, db1, seq, h1f, c1f, fw, fb, out);
    }
}